// Round 5
// baseline (537.976 us; speedup 1.0000x reference)
//
#include <hip/hip_runtime.h>
#include <cmath>
#include <cstdint>
#include <cstddef>

#define HID 64
#define NGR 128            // B graphs
#define NTOT 131072        // 128 * 1024 nodes, fixed index space all layers
#define EDGES 1048576      // B * 1024 * 8
#define EPG 8192           // edges per graph
#define CPAD 9216          // padded CSR stride (u16): 8192 + 1024 worst-case pads
#define SENT 1024          // sentinel src index -> reads 0

// ---------- once: pack edges, degree hist, even-padded CSR, dinv ----------
__global__ __launch_bounds__(256) void pack_init(
    const int* __restrict__ ei, uint32_t* __restrict__ packed,
    uint16_t* __restrict__ csr_g, uint32_t* __restrict__ rs_g,
    float* __restrict__ dinv_g, float* __restrict__ sums3,
    float* __restrict__ readout) {
  __shared__ int hist[1024];
  __shared__ int part[256];
  __shared__ int cursor[1024];
  int b = blockIdx.x, t = threadIdx.x;
  for (int i = t; i < 1024; i += 256) hist[i] = 0;
  __syncthreads();
  int ebase = b * EPG, nbase = b << 10;
  for (int e = t; e < EPG; e += 256) {
    uint32_t s = (uint32_t)(ei[ebase + e] - nbase);
    uint32_t d = (uint32_t)(ei[EDGES + ebase + e] - nbase);
    packed[ebase + e] = s | (d << 10);
    atomicAdd(&hist[(int)d], 1);
  }
  __syncthreads();
  int h0 = hist[t * 4], h1 = hist[t * 4 + 1], h2 = hist[t * 4 + 2], h3 = hist[t * 4 + 3];
  // even-padded row lengths
  int p0 = h0 + (h0 & 1), p1 = h1 + (h1 & 1), p2 = h2 + (h2 & 1), p3 = h3 + (h3 & 1);
  int tot = p0 + p1 + p2 + p3;
  part[t] = tot;
  __syncthreads();
  for (int off = 1; off < 256; off <<= 1) {
    int v = (t >= off) ? part[t - off] : 0;
    __syncthreads();
    part[t] += v;
    __syncthreads();
  }
  int excl = part[t] - tot;
  int r0 = excl, r1 = r0 + p0, r2 = r1 + p1, r3 = r2 + p2;
  cursor[t * 4 + 0] = r0; cursor[t * 4 + 1] = r1;
  cursor[t * 4 + 2] = r2; cursor[t * 4 + 3] = r3;
  uint32_t* rg = rs_g + b * 1025;
  rg[t * 4 + 0] = r0; rg[t * 4 + 1] = r1; rg[t * 4 + 2] = r2; rg[t * 4 + 3] = r3;
  if (t == 255) rg[1024] = part[255];           // total padded length
  for (int i = t; i < 1024; i += 256)
    dinv_g[(b << 10) + i] = rsqrtf((float)hist[i] + 1.0f);
  __syncthreads();
  uint16_t* cg = csr_g + (size_t)b * CPAD;
  for (int e = t; e < EPG; e += 256) {
    uint32_t pk = packed[ebase + e];
    int d = (pk >> 10) & 1023;
    int idx = atomicAdd(&cursor[d], 1);
    cg[idx] = (uint16_t)(pk & 1023);
  }
  __syncthreads();
  // sentinel fill for odd rows (cursor[d] == pstart[d] + hist[d] now)
  for (int d = t; d < 1024; d += 256)
    if (hist[d] & 1) cg[cursor[d]] = (uint16_t)SENT;
  if (b < 3 && t < 128) sums3[b * 128 + t] = 0.0f;
  if (t < 128) readout[b * 128 + t] = 0.0f;
}

// ---------- streaming gemm, row-major X [N][DIN] (layer 0) ----------
// 128 nodes x 64 ch per block, thread = 4 nodes x 8 ch, W LDS-resident.
template<int DIN>
__global__ __launch_bounds__(256, 4) void gemm_rm(
    const float* __restrict__ X, const float* __restrict__ W,
    float* __restrict__ XWT) {
  __shared__ float sW[DIN * 64];       // 32 KB for DIN=128
  const int t = threadIdx.x;
  const int c8 = (t & 7) * 8;
  const int n4 = (t >> 3) * 4;
  const int node0 = blockIdx.x * 128;
#pragma unroll
  for (int i = t; i < DIN * 16; i += 256)
    ((float4*)sW)[i] = ((const float4*)W)[i];
  __syncthreads();

  float acc[4][8];
#pragma unroll
  for (int i = 0; i < 4; i++)
#pragma unroll
    for (int c = 0; c < 8; c++) acc[i][c] = 0.0f;

  const float* xp = X + (size_t)(node0 + n4) * DIN;
#pragma unroll 8
  for (int k0 = 0; k0 < DIN; k0 += 4) {
    float x4[4][4];
#pragma unroll
    for (int i = 0; i < 4; i++) {
      float4 v = *(const float4*)(xp + (size_t)i * DIN + k0);
      x4[i][0] = v.x; x4[i][1] = v.y; x4[i][2] = v.z; x4[i][3] = v.w;
    }
#pragma unroll
    for (int j = 0; j < 4; j++) {
      float4 w0 = *(const float4*)(sW + (k0 + j) * 64 + c8);
      float4 w1 = *(const float4*)(sW + (k0 + j) * 64 + c8 + 4);
      float wn[8] = {w0.x, w0.y, w0.z, w0.w, w1.x, w1.y, w1.z, w1.w};
#pragma unroll
      for (int i = 0; i < 4; i++)
#pragma unroll
        for (int c = 0; c < 8; c++)
          acc[i][c] = fmaf(x4[i][j], wn[c], acc[i][c]);
    }
  }
#pragma unroll
  for (int c = 0; c < 8; c++) {
    float* o = XWT + (size_t)(c8 + c) * NTOT + node0 + n4;
    *(float4*)o = make_float4(acc[0][c], acc[1][c], acc[2][c], acc[3][c]);
  }
}

// ---------- fused gemm for layers 1,2: xw = (BN_relu(h)*mult) @ W ----------
// Reads previous layer's hT [64][NTOT] directly; applies y = relu(h*sc+sh)*mult
// on the fly (mult = kept ? tanh(score) : 0, node-indexed) so the pooled x
// matrix is never materialized. W LDS-resident; per-k extra cost is 12 VALU
// vs 32 FMA.
template<int DIN>
__global__ __launch_bounds__(256, 4) void gemm_fused(
    const float* __restrict__ H, const float* __restrict__ sums,
    const float* __restrict__ gamma, const float* __restrict__ beta,
    const float* __restrict__ mult_g, const float* __restrict__ W,
    float* __restrict__ XWT, float inv_n) {
  __shared__ float sW[DIN * 64];       // 16 KB for DIN=64
  __shared__ float ssc[DIN], ssh[DIN];
  const int t = threadIdx.x;
  const int c8 = (t & 7) * 8;
  const int n4 = (t >> 3) * 4;
  const int node0 = blockIdx.x * 128;
#pragma unroll
  for (int i = t; i < DIN * 16; i += 256)
    ((float4*)sW)[i] = ((const float4*)W)[i];
  if (t < DIN) {
    float mu = sums[t] * inv_n;
    float var = fmaxf(sums[64 + t] * inv_n - mu * mu, 0.0f);
    float sc = rsqrtf(var + 1e-5f) * gamma[t];
    ssc[t] = sc; ssh[t] = beta[t] - mu * sc;
  }
  __syncthreads();

  float acc[4][8];
#pragma unroll
  for (int i = 0; i < 4; i++)
#pragma unroll
    for (int c = 0; c < 8; c++) acc[i][c] = 0.0f;

  const float4 m4 = *(const float4*)(mult_g + node0 + n4);
  const float* hp = H + node0 + n4;
#pragma unroll 8
  for (int kk = 0; kk < DIN; kk++) {
    float4 h4 = *(const float4*)(hp + (size_t)kk * NTOT);
    float scc = ssc[kk], shh = ssh[kk];
    float xn[4];
    xn[0] = fmaxf(fmaf(h4.x, scc, shh), 0.0f) * m4.x;
    xn[1] = fmaxf(fmaf(h4.y, scc, shh), 0.0f) * m4.y;
    xn[2] = fmaxf(fmaf(h4.z, scc, shh), 0.0f) * m4.z;
    xn[3] = fmaxf(fmaf(h4.w, scc, shh), 0.0f) * m4.w;
    float4 w0 = *(const float4*)(sW + kk * 64 + c8);
    float4 w1 = *(const float4*)(sW + kk * 64 + c8 + 4);
    float wn[8] = {w0.x, w0.y, w0.z, w0.w, w1.x, w1.y, w1.z, w1.w};
#pragma unroll
    for (int i = 0; i < 4; i++)
#pragma unroll
      for (int c = 0; c < 8; c++)
        acc[i][c] = fmaf(xn[i], wn[c], acc[i][c]);
  }
#pragma unroll
  for (int c = 0; c < 8; c++) {
    float* o = XWT + (size_t)(c8 + c) * NTOT + node0 + n4;
    *(float4*)o = make_float4(acc[0][c], acc[1][c], acc[2][c], acc[3][c]);
  }
}

// ---------- CSR aggregate (paired u32 src reads) + self-loop + bias + BN sums ----------
__global__ __launch_bounds__(1024, 8) void edge_agg(
    const uint16_t* __restrict__ csr_g, const uint32_t* __restrict__ rs_g,
    const float* __restrict__ dinv_g, const float* __restrict__ xwT,
    const float* __restrict__ bias, float* __restrict__ hT,
    float* __restrict__ sums) {
  __shared__ float xws[8 * 1028];      // prescaled xw*dinv; index 1024 = sentinel 0
  __shared__ float dv[1024];
  __shared__ uint32_t rs[1025];
  __shared__ uint32_t csr_s[CPAD / 2]; // 4608 u32 = 18.4 KB (pairs of u16 srcs)
  __shared__ float sredS[16][8], sredQ[16][8];
  const int g = blockIdx.x & 127;
  const int q = blockIdx.x >> 7;
  const int c0 = q * 8;
  const int t = threadIdx.x;
  const int gbase = g << 10;

  dv[t] = dinv_g[gbase + t];
  rs[t] = rs_g[g * 1025 + t];
  if (t == 0) rs[1024] = rs_g[g * 1025 + 1024];
  {
    const uint4* src4 = (const uint4*)(csr_g + (size_t)g * CPAD);
    ((uint4*)csr_s)[t] = src4[t];
    if (t < CPAD / 8 - 1024) ((uint4*)csr_s)[1024 + t] = src4[1024 + t];
  }
  for (int slot = t; slot < 2048; slot += 1024) {
    int c = slot >> 8, pos4 = (slot & 255) * 4;
    float4 v = *(const float4*)(xwT + (size_t)(c0 + c) * NTOT + gbase + pos4);
    float4 dd = *(const float4*)(dinv_g + gbase + pos4);
    v.x *= dd.x; v.y *= dd.y; v.z *= dd.z; v.w *= dd.w;
    *(float4*)(xws + c * 1028 + pos4) = v;
  }
  if (t < 32) xws[(t >> 2) * 1028 + 1024 + (t & 3)] = 0.0f;   // sentinel slots
  __syncthreads();

  const int c = t & 7, j = t >> 3;
  const float* xc = xws + c * 1028;
  const float bv = bias[c0 + c];
  float* hrow = hT + (size_t)(c0 + c) * NTOT + gbase;
  float S = 0.0f, Q = 0.0f;
  for (int d = j; d < 1024; d += 128) {
    float dvd = dv[d];
    if (dvd == 0.0f) continue;
    int e  = rs[d] >> 1;
    int e1 = rs[d + 1] >> 1;
    float a0 = 0.0f, a1 = 0.0f;
    for (; e < e1; e++) {
      uint32_t pk = csr_s[e];
      a0 += xc[pk & 0xFFFFu];
      a1 += xc[pk >> 16];
    }
    float hv = (a0 + a1 + xc[d]) * dvd + bv;
    hrow[d] = hv;
    S += hv; Q += hv * hv;
  }
#pragma unroll
  for (int m = 8; m < 64; m <<= 1) { S += __shfl_xor(S, m); Q += __shfl_xor(Q, m); }
  {
    int lane = t & 63, w = t >> 6;
    if (lane < 8) { sredS[w][lane] = S; sredQ[w][lane] = Q; }
  }
  __syncthreads();
  if (t < 8) {
    float a = 0.0f;
    for (int w2 = 0; w2 < 16; w2++) a += sredS[w2][t];
    atomicAdd(&sums[c0 + t], a);
  } else if (t < 16) {
    int cc = t - 8;
    float a = 0.0f;
    for (int w2 = 0; w2 < 16; w2++) a += sredQ[w2][cc];
    atomicAdd(&sums[64 + cc + c0], a);
  }
}

// ---------- fused score + topk + readout + next-dinv, one block per graph ----------
// Phase 1: per-node score (BN+ReLU+dot p). Phase 2: exact rank count vs all
// 1024 scores (LDS broadcast reads). Phase 3: per-channel S/M readout over the
// L2-resident hT slice. Phase 4: next-layer dinv via CSR walk on kept mask.
// Outputs: mult_g (kept ? tanh(v) : 0), dinv_g in-place, readout +=.
__global__ __launch_bounds__(1024) void sctp_kernel(
    const float* __restrict__ hT, const float* __restrict__ sums,
    const float* __restrict__ gamma, const float* __restrict__ beta,
    const float* __restrict__ p,
    const uint16_t* __restrict__ csr_g, const uint32_t* __restrict__ rs_g,
    float* __restrict__ dinv_g, float* __restrict__ mult_g,
    float* __restrict__ readout, int k, float inv_n, int hasNext) {
  __shared__ float __align__(16) ssc2[4 * 260];   // scores, quarter q at q*260
  __shared__ float ssc[64], ssh[64], sp[64];
  __shared__ float sipn;
  __shared__ float mult_l[1024];
  __shared__ int skn_l[1025];          // [1024] = 0 for sentinel
  __shared__ float redS[64], redM[64];
  const int g = blockIdx.x;
  const int t = threadIdx.x;
  const int gbase = g << 10;

  if (t < 64) {
    float mu = sums[t] * inv_n;
    float var = fmaxf(sums[64 + t] * inv_n - mu * mu, 0.0f);
    float sc = rsqrtf(var + 1e-5f) * gamma[t];
    ssc[t] = sc; ssh[t] = beta[t] - mu * sc;
    sp[t] = p[t];
  }
  if (t == 1023) skn_l[1024] = 0;
  __syncthreads();
  if (t == 0) {
    float s = 0.0f;
    for (int i = 0; i < 64; i++) s += sp[i] * sp[i];
    sipn = rsqrtf(s);
  }
  __syncthreads();

  // ---- phase 1: score for node t ----
  const float* hp = hT + gbase + t;
  float s0 = 0.0f;
#pragma unroll 16
  for (int c = 0; c < 64; c++) {
    float y = fmaxf(fmaf(hp[(size_t)c * NTOT], ssc[c], ssh[c]), 0.0f);
    s0 = fmaf(y, sp[c], s0);
  }
  float v0 = s0 * sipn;
  float dvv = dinv_g[gbase + t];
  float my = (dvv > 0.0f) ? v0 : -INFINITY;
  float th = tanhf(v0);
  ssc2[(t >> 8) * 260 + (t & 255)] = my;
  __syncthreads();

  // ---- phase 2: rank of node t among all 1024 (broadcast LDS reads) ----
  int r = 0;
#pragma unroll
  for (int q4 = 0; q4 < 4; q4++) {
    const float4* base = (const float4*)(ssc2 + q4 * 260);
    int jbase = q4 * 256;
#pragma unroll 8
    for (int m = 0; m < 64; m++) {
      float4 v = base[m];
      int j0 = jbase + m * 4;
      r += (v.x > my) || (v.x == my && (j0 + 0) < t);
      r += (v.y > my) || (v.y == my && (j0 + 1) < t);
      r += (v.z > my) || (v.z == my && (j0 + 2) < t);
      r += (v.w > my) || (v.w == my && (j0 + 3) < t);
    }
  }
  int kn = (r < k) ? 1 : 0;
  skn_l[t] = kn;
  float mt = kn ? th : 0.0f;
  mult_l[t] = mt;
  mult_g[gbase + t] = mt;
  __syncthreads();

  // ---- phase 3: readout reductions; wave w handles channels w, w+16, w+32, w+48 ----
  const int w = t >> 6, lane = t & 63;
#pragma unroll
  for (int rep = 0; rep < 4; rep++) {
    int c = w + rep * 16;
    const float* hrow = hT + (size_t)c * NTOT + gbase;
    float scc = ssc[c], shh = ssh[c];
    float S = 0.0f, M = -INFINITY;
#pragma unroll
    for (int j = 0; j < 16; j++) {
      int nd = lane + j * 64;
      float y = fmaxf(fmaf(hrow[nd], scc, shh), 0.0f) * mult_l[nd];
      S += y;
      M = skn_l[nd] ? fmaxf(M, y) : M;
    }
#pragma unroll
    for (int m = 1; m < 64; m <<= 1) {
      S += __shfl_xor(S, m);
      M = fmaxf(M, __shfl_xor(M, m));
    }
    if (lane == 0) { redS[c] = S; redM[c] = M; }
  }

  // ---- phase 4: next-layer dinv (CSR walk over kept mask) ----
  if (hasNext) {
    if (skn_l[t]) {
      uint32_t e0 = rs_g[g * 1025 + t], e1 = rs_g[g * 1025 + t + 1];
      const uint16_t* row = csr_g + (size_t)g * CPAD;
      int cnt = 0;
      for (uint32_t e = e0; e < e1; e++) cnt += skn_l[row[e]];   // sentinel -> 0
      dinv_g[gbase + t] = rsqrtf((float)cnt + 1.0f);
    } else {
      dinv_g[gbase + t] = 0.0f;
    }
  }
  __syncthreads();
  if (t < 64) readout[g * 128 + t] += redS[t] / (float)k;
  else if (t < 128) readout[g * 128 + 64 + (t - 64)] += redM[t - 64];
}

// ---------------- out = readout @ Wm + bm ----------------
__global__ __launch_bounds__(256) void final_linear(
    const float* __restrict__ readout, const float* __restrict__ Wm,
    const float* __restrict__ bm, float* __restrict__ out) {
  int idx = blockIdx.x * 256 + threadIdx.x;
  if (idx >= NGR * 10) return;
  int b = idx / 10, o = idx - b * 10;
  float acc = bm[o];
  const float* r = readout + (size_t)b * 128;
  for (int c = 0; c < 128; c++) acc = fmaf(r[c], Wm[c * 10 + o], acc);
  out[idx] = acc;
}

extern "C" void kernel_launch(void* const* d_in, const int* in_sizes, int n_in,
                              void* d_out, int out_size, void* d_ws, size_t ws_size,
                              hipStream_t stream) {
  (void)in_sizes; (void)n_in; (void)out_size; (void)ws_size;
  const float* x  = (const float*)d_in[0];
  const int*   ei = (const int*)d_in[1];
  const float* Wk[3]  = {(const float*)d_in[2],  (const float*)d_in[7],  (const float*)d_in[12]};
  const float* bk[3]  = {(const float*)d_in[3],  (const float*)d_in[8],  (const float*)d_in[13]};
  const float* gk[3]  = {(const float*)d_in[4],  (const float*)d_in[9],  (const float*)d_in[14]};
  const float* btk[3] = {(const float*)d_in[5],  (const float*)d_in[10], (const float*)d_in[15]};
  const float* pk[3]  = {(const float*)d_in[6],  (const float*)d_in[11], (const float*)d_in[16]};
  const float* Wm = (const float*)d_in[17];
  const float* bm = (const float*)d_in[18];
  float* out = (float*)d_out;

  // ---- workspace carve (float units); feature buffers channel-major [64][NTOT] ----
  float* ws = (float*)d_ws;
  size_t off = 0;
  auto alloc = [&](size_t nfl) {
    float* ptr = ws + off;
    off += (nfl + 63) & ~(size_t)63;
    return ptr;
  };
  float* bufXW = alloc((size_t)NTOT * 64);
  float* bufH  = alloc((size_t)NTOT * 64);
  float* dinv_g = alloc(NTOT);
  float* mult   = alloc(NTOT);
  uint32_t* packed = (uint32_t*)alloc(EDGES);
  uint16_t* csr    = (uint16_t*)alloc((size_t)NGR * CPAD / 2);
  uint32_t* rs     = (uint32_t*)alloc(NGR * 1025);
  float* sums3 = alloc(3 * 128);
  float* readout = alloc(NGR * 2 * HID);

  pack_init<<<NGR, 256, 0, stream>>>(ei, packed, csr, rs, dinv_g, sums3, readout);

  const int   kk[3] = {820, 656, 525};
  const float invn[3] = {1.0f / (float)NTOT, 1.0f / (float)(NGR * 820),
                         1.0f / (float)(NGR * 656)};

  for (int L = 0; L < 3; L++) {
    float* sums = sums3 + L * 128;
    if (L == 0)
      gemm_rm<128><<<NTOT / 128, 256, 0, stream>>>(x, Wk[0], bufXW);
    else
      gemm_fused<64><<<NTOT / 128, 256, 0, stream>>>(
          bufH, sums3 + (L - 1) * 128, gk[L - 1], btk[L - 1],
          mult, Wk[L], bufXW, invn[L - 1]);
    edge_agg<<<8 * NGR, 1024, 0, stream>>>(csr, rs, dinv_g, bufXW, bk[L], bufH, sums);
    sctp_kernel<<<NGR, 1024, 0, stream>>>(bufH, sums, gk[L], btk[L], pk[L],
                                          csr, rs, dinv_g, mult, readout,
                                          kk[L], invn[L], (L < 2) ? 1 : 0);
  }
  final_linear<<<5, 256, 0, stream>>>(readout, Wm, bm, out);
}

// Round 6
// 488.193 us; speedup vs baseline: 1.1020x; 1.1020x over previous
//
#include <hip/hip_runtime.h>
#include <cmath>
#include <cstdint>
#include <cstddef>

#define HID 64
#define NGR 128            // B graphs
#define NTOT 131072        // 128 * 1024 nodes, fixed index space all layers
#define EDGES 1048576      // B * 1024 * 8
#define EPG 8192           // edges per graph
#define CPAD 9216          // padded CSR stride (u16): 8192 + 1024 worst-case pads
#define SENT 1024          // sentinel src index -> reads 0

// ---------- once: pack edges, degree hist, even-padded CSR, dinv ----------
__global__ __launch_bounds__(256) void pack_init(
    const int* __restrict__ ei, uint32_t* __restrict__ packed,
    uint16_t* __restrict__ csr_g, uint32_t* __restrict__ rs_g,
    float* __restrict__ dinv_g, float* __restrict__ sums3,
    float* __restrict__ readout) {
  __shared__ int hist[1024];
  __shared__ int part[256];
  __shared__ int cursor[1024];
  int b = blockIdx.x, t = threadIdx.x;
  for (int i = t; i < 1024; i += 256) hist[i] = 0;
  __syncthreads();
  int ebase = b * EPG, nbase = b << 10;
  for (int e = t; e < EPG; e += 256) {
    uint32_t s = (uint32_t)(ei[ebase + e] - nbase);
    uint32_t d = (uint32_t)(ei[EDGES + ebase + e] - nbase);
    packed[ebase + e] = s | (d << 10);
    atomicAdd(&hist[(int)d], 1);
  }
  __syncthreads();
  int h0 = hist[t * 4], h1 = hist[t * 4 + 1], h2 = hist[t * 4 + 2], h3 = hist[t * 4 + 3];
  // even-padded row lengths
  int p0 = h0 + (h0 & 1), p1 = h1 + (h1 & 1), p2 = h2 + (h2 & 1), p3 = h3 + (h3 & 1);
  int tot = p0 + p1 + p2 + p3;
  part[t] = tot;
  __syncthreads();
  for (int off = 1; off < 256; off <<= 1) {
    int v = (t >= off) ? part[t - off] : 0;
    __syncthreads();
    part[t] += v;
    __syncthreads();
  }
  int excl = part[t] - tot;
  int r0 = excl, r1 = r0 + p0, r2 = r1 + p1, r3 = r2 + p2;
  cursor[t * 4 + 0] = r0; cursor[t * 4 + 1] = r1;
  cursor[t * 4 + 2] = r2; cursor[t * 4 + 3] = r3;
  uint32_t* rg = rs_g + b * 1025;
  rg[t * 4 + 0] = r0; rg[t * 4 + 1] = r1; rg[t * 4 + 2] = r2; rg[t * 4 + 3] = r3;
  if (t == 255) rg[1024] = part[255];           // total padded length
  for (int i = t; i < 1024; i += 256)
    dinv_g[(b << 10) + i] = rsqrtf((float)hist[i] + 1.0f);
  __syncthreads();
  uint16_t* cg = csr_g + (size_t)b * CPAD;
  for (int e = t; e < EPG; e += 256) {
    uint32_t pk = packed[ebase + e];
    int d = (pk >> 10) & 1023;
    int idx = atomicAdd(&cursor[d], 1);
    cg[idx] = (uint16_t)(pk & 1023);
  }
  __syncthreads();
  // sentinel fill for odd rows (cursor[d] == pstart[d] + hist[d] now)
  for (int d = t; d < 1024; d += 256)
    if (hist[d] & 1) cg[cursor[d]] = (uint16_t)SENT;
  if (b < 3 && t < 128) sums3[b * 128 + t] = 0.0f;
  if (t < 128) readout[b * 128 + t] = 0.0f;
}

// ---------- layer-0 gemm: X row-major [N][128], single-stage LDS ----------
// 64-node x 64-ch tile. Whole X-tile (64x128, pad-132 rows: 33.8 KB) + whole W
// (32 KB) staged ONCE -> one barrier, then one uninterrupted FMA burst
// (~4096 cyc/SIMD). 2 blocks/CU: neighbor's staging hides under this burst.
__global__ __launch_bounds__(256, 2) void gemm_l0(
    const float* __restrict__ X, const float* __restrict__ W,
    float* __restrict__ XWT) {
  __shared__ float sW[128 * 64];       // 32 KB
  __shared__ float xs[64 * 132];       // 33.8 KB, row stride 132 (16B-aligned)
  const int t = threadIdx.x;
  const int node0 = blockIdx.x * 64;
#pragma unroll
  for (int i = t; i < 2048; i += 256)
    ((float4*)sW)[i] = ((const float4*)W)[i];
#pragma unroll
  for (int i = t; i < 2048; i += 256) {
    int n = i >> 5, kq = (i & 31) << 2;
    *(float4*)(xs + n * 132 + kq) =
        *(const float4*)(X + (size_t)(node0 + n) * 128 + kq);
  }
  __syncthreads();

  const int c8 = (t & 7) * 8;
  const int n2 = (t >> 3) * 2;
  float acc[2][8];
#pragma unroll
  for (int i = 0; i < 2; i++)
#pragma unroll
    for (int c = 0; c < 8; c++) acc[i][c] = 0.0f;

#pragma unroll 4
  for (int k0 = 0; k0 < 128; k0 += 4) {
    float4 xa4 = *(const float4*)(xs + n2 * 132 + k0);
    float4 xb4 = *(const float4*)(xs + (n2 + 1) * 132 + k0);
    float xa[4] = {xa4.x, xa4.y, xa4.z, xa4.w};
    float xb[4] = {xb4.x, xb4.y, xb4.z, xb4.w};
#pragma unroll
    for (int j = 0; j < 4; j++) {
      float4 w0 = *(const float4*)(sW + (k0 + j) * 64 + c8);
      float4 w1 = *(const float4*)(sW + (k0 + j) * 64 + c8 + 4);
      float wn[8] = {w0.x, w0.y, w0.z, w0.w, w1.x, w1.y, w1.z, w1.w};
#pragma unroll
      for (int c = 0; c < 8; c++) {
        acc[0][c] = fmaf(xa[j], wn[c], acc[0][c]);
        acc[1][c] = fmaf(xb[j], wn[c], acc[1][c]);
      }
    }
  }
#pragma unroll
  for (int c = 0; c < 8; c++) {
    float2 st; st.x = acc[0][c]; st.y = acc[1][c];
    *(float2*)(XWT + (size_t)(c8 + c) * NTOT + node0 + n2) = st;
  }
}

// ---------- layers 1,2 gemm: X channel-major [64][NTOT], single-stage LDS ----
// 128-node x 64-ch tile. X-tile 32 KB + W 16 KB = 48 KB -> 3 blocks/CU.
// One barrier, then 64-k FMA burst; 3-deep block pipeline hides staging.
__global__ __launch_bounds__(256, 3) void gemm_l12(
    const float* __restrict__ X, const float* __restrict__ W,
    float* __restrict__ XWT) {
  __shared__ float sW[64 * 64];        // 16 KB
  __shared__ float xs[64 * 128];       // 32 KB, [k][128] linear
  const int t = threadIdx.x;
  const int node0 = blockIdx.x * 128;
  const float* Xp = X + node0;
#pragma unroll
  for (int i = t; i < 1024; i += 256)
    ((float4*)sW)[i] = ((const float4*)W)[i];
#pragma unroll
  for (int i = t; i < 2048; i += 256) {
    int k = i >> 5, q = i & 31;
    ((float4*)xs)[i] = *((const float4*)(Xp + (size_t)k * NTOT) + q);
  }
  __syncthreads();

  const int c8 = (t & 7) * 8;
  const int n4 = (t >> 3) * 4;
  float acc[4][8];
#pragma unroll
  for (int i = 0; i < 4; i++)
#pragma unroll
    for (int c = 0; c < 8; c++) acc[i][c] = 0.0f;

#pragma unroll 8
  for (int k = 0; k < 64; k++) {
    float4 x4 = *(const float4*)(xs + k * 128 + n4);
    float xn[4] = {x4.x, x4.y, x4.z, x4.w};
    float4 w0 = *(const float4*)(sW + k * 64 + c8);
    float4 w1 = *(const float4*)(sW + k * 64 + c8 + 4);
    float wn[8] = {w0.x, w0.y, w0.z, w0.w, w1.x, w1.y, w1.z, w1.w};
#pragma unroll
    for (int i = 0; i < 4; i++)
#pragma unroll
      for (int c = 0; c < 8; c++)
        acc[i][c] = fmaf(xn[i], wn[c], acc[i][c]);
  }
#pragma unroll
  for (int c = 0; c < 8; c++) {
    float* o = XWT + (size_t)(c8 + c) * NTOT + node0 + n4;
    *(float4*)o = make_float4(acc[0][c], acc[1][c], acc[2][c], acc[3][c]);
  }
}

// ---------- CSR aggregate (paired u32 src reads) + self-loop + bias + BN sums ----------
__global__ __launch_bounds__(1024, 8) void edge_agg(
    const uint16_t* __restrict__ csr_g, const uint32_t* __restrict__ rs_g,
    const float* __restrict__ dinv_g, const float* __restrict__ xwT,
    const float* __restrict__ bias, float* __restrict__ hT,
    float* __restrict__ sums) {
  __shared__ float xws[8 * 1028];      // prescaled xw*dinv; index 1024 = sentinel 0
  __shared__ float dv[1024];
  __shared__ uint32_t rs[1025];
  __shared__ uint32_t csr_s[CPAD / 2]; // 4608 u32 = 18.4 KB (pairs of u16 srcs)
  __shared__ float sredS[16][8], sredQ[16][8];
  const int g = blockIdx.x & 127;
  const int q = blockIdx.x >> 7;
  const int c0 = q * 8;
  const int t = threadIdx.x;
  const int gbase = g << 10;

  dv[t] = dinv_g[gbase + t];
  rs[t] = rs_g[g * 1025 + t];
  if (t == 0) rs[1024] = rs_g[g * 1025 + 1024];
  {
    const uint4* src4 = (const uint4*)(csr_g + (size_t)g * CPAD);
    ((uint4*)csr_s)[t] = src4[t];
    if (t < CPAD / 8 - 1024) ((uint4*)csr_s)[1024 + t] = src4[1024 + t];
  }
  for (int slot = t; slot < 2048; slot += 1024) {
    int c = slot >> 8, pos4 = (slot & 255) * 4;
    float4 v = *(const float4*)(xwT + (size_t)(c0 + c) * NTOT + gbase + pos4);
    float4 dd = *(const float4*)(dinv_g + gbase + pos4);
    v.x *= dd.x; v.y *= dd.y; v.z *= dd.z; v.w *= dd.w;
    *(float4*)(xws + c * 1028 + pos4) = v;
  }
  if (t < 32) xws[(t >> 2) * 1028 + 1024 + (t & 3)] = 0.0f;   // sentinel slots
  __syncthreads();

  const int c = t & 7, j = t >> 3;
  const float* xc = xws + c * 1028;
  const float bv = bias[c0 + c];
  float* hrow = hT + (size_t)(c0 + c) * NTOT + gbase;
  float S = 0.0f, Q = 0.0f;
  for (int d = j; d < 1024; d += 128) {
    float dvd = dv[d];
    if (dvd == 0.0f) continue;
    int e  = rs[d] >> 1;
    int e1 = rs[d + 1] >> 1;
    float a0 = 0.0f, a1 = 0.0f;
    for (; e < e1; e++) {
      uint32_t pk = csr_s[e];
      a0 += xc[pk & 0xFFFFu];
      a1 += xc[pk >> 16];
    }
    float hv = (a0 + a1 + xc[d]) * dvd + bv;
    hrow[d] = hv;
    S += hv; Q += hv * hv;
  }
#pragma unroll
  for (int m = 8; m < 64; m <<= 1) { S += __shfl_xor(S, m); Q += __shfl_xor(Q, m); }
  {
    int lane = t & 63, w = t >> 6;
    if (lane < 8) { sredS[w][lane] = S; sredQ[w][lane] = Q; }
  }
  __syncthreads();
  if (t < 8) {
    float a = 0.0f;
    for (int w2 = 0; w2 < 16; w2++) a += sredS[w2][t];
    atomicAdd(&sums[c0 + t], a);
  } else if (t < 16) {
    int cc = t - 8;
    float a = 0.0f;
    for (int w2 = 0; w2 < 16; w2++) a += sredQ[w2][cc];
    atomicAdd(&sums[64 + cc + c0], a);
  }
}

// ---------- scores: BN+ReLU+dot(p) per node; grid = NGR*4 x 256 ----------
__global__ __launch_bounds__(256) void score_kernel(
    const float* __restrict__ hT, const float* __restrict__ sums,
    const float* __restrict__ gamma, const float* __restrict__ beta,
    const float* __restrict__ p, const float* __restrict__ dinv_g,
    float* __restrict__ score, float* __restrict__ stanh_g, float inv_n) {
  __shared__ float ssc[64], ssh[64], sp[64];
  __shared__ float sipn;
  int b = blockIdx.x >> 2, seg = (blockIdx.x & 3) << 8;
  int t = threadIdx.x;
  int node = (b << 10) + seg + t;
  if (t < 64) {
    float mu = sums[t] * inv_n;
    float var = fmaxf(sums[64 + t] * inv_n - mu * mu, 0.0f);
    float sc = rsqrtf(var + 1e-5f) * gamma[t];
    ssc[t] = sc; ssh[t] = beta[t] - mu * sc;
    sp[t] = p[t];
  }
  __syncthreads();
  if (t == 0) {
    float s = 0.0f;
    for (int i = 0; i < 64; i++) s += sp[i] * sp[i];
    sipn = rsqrtf(s);
  }
  __syncthreads();
  const float* hp = hT + node;
  float s0 = 0.0f;
#pragma unroll 16
  for (int c = 0; c < 64; c++) {
    float y = fmaxf(fmaf(hp[(size_t)c * NTOT], ssc[c], ssh[c]), 0.0f);
    s0 = fmaf(y, sp[c], s0);
  }
  float v0 = s0 * sipn;
  score[node] = (dinv_g[node] > 0.0f) ? v0 : -INFINITY;
  stanh_g[node] = tanhf(v0);
}

// ---------- topk: 4 blocks/graph, 4-way j-split rank count -> kept mask ----------
__global__ __launch_bounds__(1024) void topk_kernel(
    const float* __restrict__ score, int* __restrict__ snext_g, int k) {
  __shared__ float __align__(16) ssc2[4 * 260];   // quarter q at offset q*260
  int b = blockIdx.x >> 2, p = blockIdx.x & 3;
  int t = threadIdx.x;
  int gbase = b << 10;
  float sv = score[gbase + t];
  ssc2[(t >> 8) * 260 + (t & 255)] = sv;
  __syncthreads();
  int il = t >> 2, jq = t & 3;
  int gi = p * 256 + il;
  float my = ssc2[(gi >> 8) * 260 + (gi & 255)];
  const float4* base = (const float4*)(ssc2 + jq * 260);
  int jbase = jq * 256;
  int r = 0;
#pragma unroll 8
  for (int m = 0; m < 64; m++) {
    float4 v = base[m];
    int j0 = jbase + m * 4;
    r += (v.x > my) || (v.x == my && (j0 + 0) < gi);
    r += (v.y > my) || (v.y == my && (j0 + 1) < gi);
    r += (v.z > my) || (v.z == my && (j0 + 2) < gi);
    r += (v.w > my) || (v.w == my && (j0 + 3) < gi);
  }
  r += __shfl_xor(r, 1);
  r += __shfl_xor(r, 2);
  if (jq == 0) snext_g[gbase + gi] = (r < k) ? 1 : 0;
}

// ---------- masked pool + readout accumulate + next-layer dinv (CSR walk) ----------
__global__ __launch_bounds__(256) void pool_kernel(
    const float* __restrict__ hT, const float* __restrict__ sums,
    const float* __restrict__ gamma, const float* __restrict__ beta,
    const float* __restrict__ stanh_g, const int* __restrict__ snext_g,
    const uint16_t* __restrict__ csr_g, const uint32_t* __restrict__ rs_g,
    float* __restrict__ xT_out, float* __restrict__ dinv_g,
    float* __restrict__ readout, int k, float inv_n, int hasNext) {
  __shared__ float ssc[64], ssh[64];
  __shared__ float sth[1024];
  __shared__ int skn[1025];            // [1024] = 0 for sentinel
  __shared__ float redS[4][8], redM[4][8];
  int g = blockIdx.x & 127, q = blockIdx.x >> 7;
  int t = threadIdx.x;
  int gbase = g << 10;
  if (t < 64) {
    float mu = sums[t] * inv_n;
    float var = fmaxf(sums[64 + t] * inv_n - mu * mu, 0.0f);
    float sc = rsqrtf(var + 1e-5f) * gamma[t];
    ssc[t] = sc; ssh[t] = beta[t] - mu * sc;
  }
  for (int i = t; i < 1024; i += 256) {
    sth[i] = stanh_g[gbase + i];
    skn[i] = snext_g[gbase + i];
  }
  if (t == 0) skn[1024] = 0;
  __syncthreads();
  int lane = t & 63, w = t >> 6;
#pragma unroll
  for (int i = 0; i < 8; i++) {
    int c = q * 8 + i;
    const float* hrow = hT + (size_t)c * NTOT + gbase;
    float* xrow = xT_out ? (xT_out + (size_t)c * NTOT + gbase) : nullptr;
    float scc = ssc[c], shh = ssh[c];
    float S = 0.0f, M = -INFINITY;
    for (int nd = t; nd < 1024; nd += 256) {
      bool kn = skn[nd] != 0;
      float y = fmaxf(fmaf(hrow[nd], scc, shh), 0.0f) * sth[nd];
      y = kn ? y : 0.0f;
      if (xrow) xrow[nd] = y;
      S += y;
      if (kn) M = fmaxf(M, y);
    }
#pragma unroll
    for (int m = 1; m < 64; m <<= 1) {
      S += __shfl_xor(S, m);
      M = fmaxf(M, __shfl_xor(M, m));
    }
    if (lane == 0) { redS[w][i] = S; redM[w][i] = M; }
  }
  if (hasNext && t < 128) {
    int d = q * 128 + t;
    if (skn[d]) {
      uint32_t e0 = rs_g[g * 1025 + d], e1 = rs_g[g * 1025 + d + 1];
      const uint16_t* row = csr_g + (size_t)g * CPAD;
      int cnt = 0;
      for (uint32_t e = e0; e < e1; e++) cnt += skn[row[e]];   // sentinel -> 0
      dinv_g[gbase + d] = rsqrtf((float)cnt + 1.0f);
    } else {
      dinv_g[gbase + d] = 0.0f;
    }
  }
  __syncthreads();
  if (t < 8) {
    float S = redS[0][t] + redS[1][t] + redS[2][t] + redS[3][t];
    readout[g * 128 + q * 8 + t] += S / (float)k;
  } else if (t < 16) {
    int i = t - 8;
    float M = fmaxf(fmaxf(redM[0][i], redM[1][i]), fmaxf(redM[2][i], redM[3][i]));
    readout[g * 128 + 64 + q * 8 + i] += M;
  }
}

// ---------------- out = readout @ Wm + bm ----------------
__global__ __launch_bounds__(256) void final_linear(
    const float* __restrict__ readout, const float* __restrict__ Wm,
    const float* __restrict__ bm, float* __restrict__ out) {
  int idx = blockIdx.x * 256 + threadIdx.x;
  if (idx >= NGR * 10) return;
  int b = idx / 10, o = idx - b * 10;
  float acc = bm[o];
  const float* r = readout + (size_t)b * 128;
  for (int c = 0; c < 128; c++) acc = fmaf(r[c], Wm[c * 10 + o], acc);
  out[idx] = acc;
}

extern "C" void kernel_launch(void* const* d_in, const int* in_sizes, int n_in,
                              void* d_out, int out_size, void* d_ws, size_t ws_size,
                              hipStream_t stream) {
  (void)in_sizes; (void)n_in; (void)out_size; (void)ws_size;
  const float* x  = (const float*)d_in[0];
  const int*   ei = (const int*)d_in[1];
  const float* Wk[3]  = {(const float*)d_in[2],  (const float*)d_in[7],  (const float*)d_in[12]};
  const float* bk[3]  = {(const float*)d_in[3],  (const float*)d_in[8],  (const float*)d_in[13]};
  const float* gk[3]  = {(const float*)d_in[4],  (const float*)d_in[9],  (const float*)d_in[14]};
  const float* btk[3] = {(const float*)d_in[5],  (const float*)d_in[10], (const float*)d_in[15]};
  const float* pk[3]  = {(const float*)d_in[6],  (const float*)d_in[11], (const float*)d_in[16]};
  const float* Wm = (const float*)d_in[17];
  const float* bm = (const float*)d_in[18];
  float* out = (float*)d_out;

  // ---- workspace carve (float units); feature buffers channel-major [64][NTOT] ----
  float* ws = (float*)d_ws;
  size_t off = 0;
  auto alloc = [&](size_t nfl) {
    float* ptr = ws + off;
    off += (nfl + 63) & ~(size_t)63;
    return ptr;
  };
  float* bufXW = alloc((size_t)NTOT * 64);
  float* bufH  = alloc((size_t)NTOT * 64);
  float* bufX  = alloc((size_t)NTOT * 64);
  float* dinv_g = alloc(NTOT);
  float* score  = alloc(NTOT);
  float* stanh_g = alloc(NTOT);
  int*   snext_g = (int*)alloc(NTOT);
  uint32_t* packed = (uint32_t*)alloc(EDGES);
  uint16_t* csr    = (uint16_t*)alloc((size_t)NGR * CPAD / 2);
  uint32_t* rs     = (uint32_t*)alloc(NGR * 1025);
  float* sums3 = alloc(3 * 128);
  float* readout = alloc(NGR * 2 * HID);

  pack_init<<<NGR, 256, 0, stream>>>(ei, packed, csr, rs, dinv_g, sums3, readout);

  const int   kk[3] = {820, 656, 525};
  const float invn[3] = {1.0f / (float)NTOT, 1.0f / (float)(NGR * 820),
                         1.0f / (float)(NGR * 656)};

  for (int L = 0; L < 3; L++) {
    float* sums = sums3 + L * 128;
    if (L == 0)
      gemm_l0<<<NTOT / 64, 256, 0, stream>>>(x, Wk[0], bufXW);
    else
      gemm_l12<<<NTOT / 128, 256, 0, stream>>>(bufX, Wk[L], bufXW);
    edge_agg<<<8 * NGR, 1024, 0, stream>>>(csr, rs, dinv_g, bufXW, bk[L], bufH, sums);
    score_kernel<<<4 * NGR, 256, 0, stream>>>(bufH, sums, gk[L], btk[L], pk[L],
                                              dinv_g, score, stanh_g, invn[L]);
    topk_kernel<<<4 * NGR, 1024, 0, stream>>>(score, snext_g, kk[L]);
    pool_kernel<<<8 * NGR, 256, 0, stream>>>(bufH, sums, gk[L], btk[L],
                                             stanh_g, snext_g, csr, rs,
                                             (L < 2) ? bufX : nullptr, dinv_g,
                                             readout, kk[L], invn[L],
                                             (L < 2) ? 1 : 0);
  }
  final_linear<<<5, 256, 0, stream>>>(readout, Wm, bm, out);
}

// Round 7
// 479.992 us; speedup vs baseline: 1.1208x; 1.0171x over previous
//
#include <hip/hip_runtime.h>
#include <cmath>
#include <cstdint>
#include <cstddef>

#define HID 64
#define NGR 128            // B graphs
#define NTOT 131072        // 128 * 1024 nodes, fixed index space all layers
#define EDGES 1048576      // B * 1024 * 8
#define EPG 8192           // edges per graph
#define CPAD 9216          // padded CSR stride (u16): 8192 + 1024 worst-case pads
#define SENT 1024          // sentinel src index -> reads 0

// ---------- once: pack edges, degree hist, even-padded CSR, dinv ----------
__global__ __launch_bounds__(256) void pack_init(
    const int* __restrict__ ei, uint32_t* __restrict__ packed,
    uint16_t* __restrict__ csr_g, uint32_t* __restrict__ rs_g,
    float* __restrict__ dinv_g, float* __restrict__ sums3,
    float* __restrict__ readout) {
  __shared__ int hist[1024];
  __shared__ int part[256];
  __shared__ int cursor[1024];
  int b = blockIdx.x, t = threadIdx.x;
  for (int i = t; i < 1024; i += 256) hist[i] = 0;
  __syncthreads();
  int ebase = b * EPG, nbase = b << 10;
  for (int e = t; e < EPG; e += 256) {
    uint32_t s = (uint32_t)(ei[ebase + e] - nbase);
    uint32_t d = (uint32_t)(ei[EDGES + ebase + e] - nbase);
    packed[ebase + e] = s | (d << 10);
    atomicAdd(&hist[(int)d], 1);
  }
  __syncthreads();
  int h0 = hist[t * 4], h1 = hist[t * 4 + 1], h2 = hist[t * 4 + 2], h3 = hist[t * 4 + 3];
  // even-padded row lengths
  int p0 = h0 + (h0 & 1), p1 = h1 + (h1 & 1), p2 = h2 + (h2 & 1), p3 = h3 + (h3 & 1);
  int tot = p0 + p1 + p2 + p3;
  part[t] = tot;
  __syncthreads();
  for (int off = 1; off < 256; off <<= 1) {
    int v = (t >= off) ? part[t - off] : 0;
    __syncthreads();
    part[t] += v;
    __syncthreads();
  }
  int excl = part[t] - tot;
  int r0 = excl, r1 = r0 + p0, r2 = r1 + p1, r3 = r2 + p2;
  cursor[t * 4 + 0] = r0; cursor[t * 4 + 1] = r1;
  cursor[t * 4 + 2] = r2; cursor[t * 4 + 3] = r3;
  uint32_t* rg = rs_g + b * 1025;
  rg[t * 4 + 0] = r0; rg[t * 4 + 1] = r1; rg[t * 4 + 2] = r2; rg[t * 4 + 3] = r3;
  if (t == 255) rg[1024] = part[255];           // total padded length
  for (int i = t; i < 1024; i += 256)
    dinv_g[(b << 10) + i] = rsqrtf((float)hist[i] + 1.0f);
  __syncthreads();
  uint16_t* cg = csr_g + (size_t)b * CPAD;
  for (int e = t; e < EPG; e += 256) {
    uint32_t pk = packed[ebase + e];
    int d = (pk >> 10) & 1023;
    int idx = atomicAdd(&cursor[d], 1);
    cg[idx] = (uint16_t)(pk & 1023);
  }
  __syncthreads();
  // sentinel fill for odd rows (cursor[d] == pstart[d] + hist[d] now)
  for (int d = t; d < 1024; d += 256)
    if (hist[d] & 1) cg[cursor[d]] = (uint16_t)SENT;
  if (b < 3 && t < 128) sums3[b * 128 + t] = 0.0f;
  if (t < 128) readout[b * 128 + t] = 0.0f;
}

// ---------- gemm8: 256-node x 64-ch tile, thread = 8 nodes x 8 ch ----------
// BK=32 k-split, k-major LDS X-tile [32][260] (pad-260: b128-aligned,
// 2-way-free compute reads). Per k: 4 ds_read_b128 feed 64 FMAs
// (24R/F = 1.5x BELOW the VALU wall; 128 cyc FMA issue covers the ~120 cyc
// LDS latency per-wave). Staging is a deep 8-load burst (many outstanding
// global loads), not in-loop trickle. Grid 512 -> 2 blocks/CU; block B's
// staging hides under block A's compute.
template<int DIN, bool CM>
__global__ __launch_bounds__(256, 2) void gemm8(
    const float* __restrict__ X, const float* __restrict__ W,
    float* __restrict__ XWT) {
  __shared__ float sW[DIN * 64];       // 32 KB (L0) / 16 KB (cm)
  __shared__ float xs[32 * 260];       // 33.3 KB
  const int t = threadIdx.x;
  const int c8 = (t & 7) * 8;
  const int n8 = (t >> 3) * 8;
  const int node0 = blockIdx.x * 256;

#pragma unroll
  for (int i = t; i < DIN * 16; i += 256)
    ((float4*)sW)[i] = ((const float4*)W)[i];

  float acc[8][8];
#pragma unroll
  for (int n = 0; n < 8; n++)
#pragma unroll
    for (int c = 0; c < 8; c++) acc[n][c] = 0.0f;

  for (int s = 0; s < DIN / 32; s++) {
    const int k0 = s * 32;
    __syncthreads();                   // xs reuse (and W visibility at s=0)
    if (CM) {
      // X [DIN][NTOT]: rows k0..k0+31, 64 f4 each -> 8 f4 per thread
#pragma unroll
      for (int i = t; i < 2048; i += 256) {
        int k = i >> 6, q = (i & 63) * 4;
        *(float4*)(xs + k * 260 + q) =
            *(const float4*)(X + (size_t)(k0 + k) * NTOT + node0 + q);
      }
    } else {
      // X [N][DIN]: 256 node-rows x 32-k chunk, transpose into k-major
#pragma unroll
      for (int i = t; i < 2048; i += 256) {
        int n = i >> 3, j4 = (i & 7) * 4;
        float4 v = *(const float4*)(X + (size_t)(node0 + n) * DIN + k0 + j4);
        xs[(j4 + 0) * 260 + n] = v.x;
        xs[(j4 + 1) * 260 + n] = v.y;
        xs[(j4 + 2) * 260 + n] = v.z;
        xs[(j4 + 3) * 260 + n] = v.w;
      }
    }
    __syncthreads();
#pragma unroll 4
    for (int k = 0; k < 32; k++) {
      const float* xr = xs + k * 260 + n8;
      float4 x0 = *(const float4*)(xr);
      float4 x1 = *(const float4*)(xr + 4);
      const float* wr = sW + (k0 + k) * 64 + c8;
      float4 w0 = *(const float4*)(wr);
      float4 w1 = *(const float4*)(wr + 4);
      float xn[8] = {x0.x, x0.y, x0.z, x0.w, x1.x, x1.y, x1.z, x1.w};
      float wn[8] = {w0.x, w0.y, w0.z, w0.w, w1.x, w1.y, w1.z, w1.w};
#pragma unroll
      for (int n = 0; n < 8; n++)
#pragma unroll
        for (int c = 0; c < 8; c++)
          acc[n][c] = fmaf(xn[n], wn[c], acc[n][c]);
    }
  }
#pragma unroll
  for (int cc = 0; cc < 8; cc++) {
    float* o = XWT + (size_t)(c8 + cc) * NTOT + node0 + n8;
    *(float4*)(o + 0) = make_float4(acc[0][cc], acc[1][cc], acc[2][cc], acc[3][cc]);
    *(float4*)(o + 4) = make_float4(acc[4][cc], acc[5][cc], acc[6][cc], acc[7][cc]);
  }
}

// ---------- CSR aggregate (paired u32 src reads) + self-loop + bias + BN sums ----------
__global__ __launch_bounds__(1024, 8) void edge_agg(
    const uint16_t* __restrict__ csr_g, const uint32_t* __restrict__ rs_g,
    const float* __restrict__ dinv_g, const float* __restrict__ xwT,
    const float* __restrict__ bias, float* __restrict__ hT,
    float* __restrict__ sums) {
  __shared__ float xws[8 * 1028];      // prescaled xw*dinv; index 1024 = sentinel 0
  __shared__ float dv[1024];
  __shared__ uint32_t rs[1025];
  __shared__ uint32_t csr_s[CPAD / 2]; // 4608 u32 = 18.4 KB (pairs of u16 srcs)
  __shared__ float sredS[16][8], sredQ[16][8];
  const int g = blockIdx.x & 127;
  const int q = blockIdx.x >> 7;
  const int c0 = q * 8;
  const int t = threadIdx.x;
  const int gbase = g << 10;

  dv[t] = dinv_g[gbase + t];
  rs[t] = rs_g[g * 1025 + t];
  if (t == 0) rs[1024] = rs_g[g * 1025 + 1024];
  {
    const uint4* src4 = (const uint4*)(csr_g + (size_t)g * CPAD);
    ((uint4*)csr_s)[t] = src4[t];
    if (t < CPAD / 8 - 1024) ((uint4*)csr_s)[1024 + t] = src4[1024 + t];
  }
  for (int slot = t; slot < 2048; slot += 1024) {
    int c = slot >> 8, pos4 = (slot & 255) * 4;
    float4 v = *(const float4*)(xwT + (size_t)(c0 + c) * NTOT + gbase + pos4);
    float4 dd = *(const float4*)(dinv_g + gbase + pos4);
    v.x *= dd.x; v.y *= dd.y; v.z *= dd.z; v.w *= dd.w;
    *(float4*)(xws + c * 1028 + pos4) = v;
  }
  if (t < 32) xws[(t >> 2) * 1028 + 1024 + (t & 3)] = 0.0f;   // sentinel slots
  __syncthreads();

  const int c = t & 7, j = t >> 3;
  const float* xc = xws + c * 1028;
  const float bv = bias[c0 + c];
  float* hrow = hT + (size_t)(c0 + c) * NTOT + gbase;
  float S = 0.0f, Q = 0.0f;
  for (int d = j; d < 1024; d += 128) {
    float dvd = dv[d];
    if (dvd == 0.0f) continue;
    int e  = rs[d] >> 1;
    int e1 = rs[d + 1] >> 1;
    float a0 = 0.0f, a1 = 0.0f;
    for (; e < e1; e++) {
      uint32_t pk = csr_s[e];
      a0 += xc[pk & 0xFFFFu];
      a1 += xc[pk >> 16];
    }
    float hv = (a0 + a1 + xc[d]) * dvd + bv;
    hrow[d] = hv;
    S += hv; Q += hv * hv;
  }
#pragma unroll
  for (int m = 8; m < 64; m <<= 1) { S += __shfl_xor(S, m); Q += __shfl_xor(Q, m); }
  {
    int lane = t & 63, w = t >> 6;
    if (lane < 8) { sredS[w][lane] = S; sredQ[w][lane] = Q; }
  }
  __syncthreads();
  if (t < 8) {
    float a = 0.0f;
    for (int w2 = 0; w2 < 16; w2++) a += sredS[w2][t];
    atomicAdd(&sums[c0 + t], a);
  } else if (t < 16) {
    int cc = t - 8;
    float a = 0.0f;
    for (int w2 = 0; w2 < 16; w2++) a += sredQ[w2][cc];
    atomicAdd(&sums[64 + cc + c0], a);
  }
}

// ---------- scores: BN+ReLU+dot(p) per node; grid = NGR*4 x 256 ----------
__global__ __launch_bounds__(256) void score_kernel(
    const float* __restrict__ hT, const float* __restrict__ sums,
    const float* __restrict__ gamma, const float* __restrict__ beta,
    const float* __restrict__ p, const float* __restrict__ dinv_g,
    float* __restrict__ score, float* __restrict__ stanh_g, float inv_n) {
  __shared__ float ssc[64], ssh[64], sp[64];
  __shared__ float sipn;
  int b = blockIdx.x >> 2, seg = (blockIdx.x & 3) << 8;
  int t = threadIdx.x;
  int node = (b << 10) + seg + t;
  if (t < 64) {
    float mu = sums[t] * inv_n;
    float var = fmaxf(sums[64 + t] * inv_n - mu * mu, 0.0f);
    float sc = rsqrtf(var + 1e-5f) * gamma[t];
    ssc[t] = sc; ssh[t] = beta[t] - mu * sc;
    sp[t] = p[t];
  }
  __syncthreads();
  if (t == 0) {
    float s = 0.0f;
    for (int i = 0; i < 64; i++) s += sp[i] * sp[i];
    sipn = rsqrtf(s);
  }
  __syncthreads();
  const float* hp = hT + node;
  float s0 = 0.0f;
#pragma unroll 16
  for (int c = 0; c < 64; c++) {
    float y = fmaxf(fmaf(hp[(size_t)c * NTOT], ssc[c], ssh[c]), 0.0f);
    s0 = fmaf(y, sp[c], s0);
  }
  float v0 = s0 * sipn;
  score[node] = (dinv_g[node] > 0.0f) ? v0 : -INFINITY;
  stanh_g[node] = tanhf(v0);
}

// ---------- topk: 4 blocks/graph, 4-way j-split rank count -> kept mask ----------
__global__ __launch_bounds__(1024) void topk_kernel(
    const float* __restrict__ score, int* __restrict__ snext_g, int k) {
  __shared__ float __align__(16) ssc2[4 * 260];   // quarter q at offset q*260
  int b = blockIdx.x >> 2, p = blockIdx.x & 3;
  int t = threadIdx.x;
  int gbase = b << 10;
  float sv = score[gbase + t];
  ssc2[(t >> 8) * 260 + (t & 255)] = sv;
  __syncthreads();
  int il = t >> 2, jq = t & 3;
  int gi = p * 256 + il;
  float my = ssc2[(gi >> 8) * 260 + (gi & 255)];
  const float4* base = (const float4*)(ssc2 + jq * 260);
  int jbase = jq * 256;
  int r = 0;
#pragma unroll 8
  for (int m = 0; m < 64; m++) {
    float4 v = base[m];
    int j0 = jbase + m * 4;
    r += (v.x > my) || (v.x == my && (j0 + 0) < gi);
    r += (v.y > my) || (v.y == my && (j0 + 1) < gi);
    r += (v.z > my) || (v.z == my && (j0 + 2) < gi);
    r += (v.w > my) || (v.w == my && (j0 + 3) < gi);
  }
  r += __shfl_xor(r, 1);
  r += __shfl_xor(r, 2);
  if (jq == 0) snext_g[gbase + gi] = (r < k) ? 1 : 0;
}

// ---------- masked pool + readout accumulate + next-layer dinv (CSR walk) ----------
__global__ __launch_bounds__(256) void pool_kernel(
    const float* __restrict__ hT, const float* __restrict__ sums,
    const float* __restrict__ gamma, const float* __restrict__ beta,
    const float* __restrict__ stanh_g, const int* __restrict__ snext_g,
    const uint16_t* __restrict__ csr_g, const uint32_t* __restrict__ rs_g,
    float* __restrict__ xT_out, float* __restrict__ dinv_g,
    float* __restrict__ readout, int k, float inv_n, int hasNext) {
  __shared__ float ssc[64], ssh[64];
  __shared__ float sth[1024];
  __shared__ int skn[1025];            // [1024] = 0 for sentinel
  __shared__ float redS[4][8], redM[4][8];
  int g = blockIdx.x & 127, q = blockIdx.x >> 7;
  int t = threadIdx.x;
  int gbase = g << 10;
  if (t < 64) {
    float mu = sums[t] * inv_n;
    float var = fmaxf(sums[64 + t] * inv_n - mu * mu, 0.0f);
    float sc = rsqrtf(var + 1e-5f) * gamma[t];
    ssc[t] = sc; ssh[t] = beta[t] - mu * sc;
  }
  for (int i = t; i < 1024; i += 256) {
    sth[i] = stanh_g[gbase + i];
    skn[i] = snext_g[gbase + i];
  }
  if (t == 0) skn[1024] = 0;
  __syncthreads();
  int lane = t & 63, w = t >> 6;
#pragma unroll
  for (int i = 0; i < 8; i++) {
    int c = q * 8 + i;
    const float* hrow = hT + (size_t)c * NTOT + gbase;
    float* xrow = xT_out ? (xT_out + (size_t)c * NTOT + gbase) : nullptr;
    float scc = ssc[c], shh = ssh[c];
    float S = 0.0f, M = -INFINITY;
    for (int nd = t; nd < 1024; nd += 256) {
      bool kn = skn[nd] != 0;
      float y = fmaxf(fmaf(hrow[nd], scc, shh), 0.0f) * sth[nd];
      y = kn ? y : 0.0f;
      if (xrow) xrow[nd] = y;
      S += y;
      if (kn) M = fmaxf(M, y);
    }
#pragma unroll
    for (int m = 1; m < 64; m <<= 1) {
      S += __shfl_xor(S, m);
      M = fmaxf(M, __shfl_xor(M, m));
    }
    if (lane == 0) { redS[w][i] = S; redM[w][i] = M; }
  }
  if (hasNext && t < 128) {
    int d = q * 128 + t;
    if (skn[d]) {
      uint32_t e0 = rs_g[g * 1025 + d], e1 = rs_g[g * 1025 + d + 1];
      const uint16_t* row = csr_g + (size_t)g * CPAD;
      int cnt = 0;
      for (uint32_t e = e0; e < e1; e++) cnt += skn[row[e]];   // sentinel -> 0
      dinv_g[gbase + d] = rsqrtf((float)cnt + 1.0f);
    } else {
      dinv_g[gbase + d] = 0.0f;
    }
  }
  __syncthreads();
  if (t < 8) {
    float S = redS[0][t] + redS[1][t] + redS[2][t] + redS[3][t];
    readout[g * 128 + q * 8 + t] += S / (float)k;
  } else if (t < 16) {
    int i = t - 8;
    float M = fmaxf(fmaxf(redM[0][i], redM[1][i]), fmaxf(redM[2][i], redM[3][i]));
    readout[g * 128 + 64 + q * 8 + i] += M;
  }
}

// ---------------- out = readout @ Wm + bm ----------------
__global__ __launch_bounds__(256) void final_linear(
    const float* __restrict__ readout, const float* __restrict__ Wm,
    const float* __restrict__ bm, float* __restrict__ out) {
  int idx = blockIdx.x * 256 + threadIdx.x;
  if (idx >= NGR * 10) return;
  int b = idx / 10, o = idx - b * 10;
  float acc = bm[o];
  const float* r = readout + (size_t)b * 128;
  for (int c = 0; c < 128; c++) acc = fmaf(r[c], Wm[c * 10 + o], acc);
  out[idx] = acc;
}

extern "C" void kernel_launch(void* const* d_in, const int* in_sizes, int n_in,
                              void* d_out, int out_size, void* d_ws, size_t ws_size,
                              hipStream_t stream) {
  (void)in_sizes; (void)n_in; (void)out_size; (void)ws_size;
  const float* x  = (const float*)d_in[0];
  const int*   ei = (const int*)d_in[1];
  const float* Wk[3]  = {(const float*)d_in[2],  (const float*)d_in[7],  (const float*)d_in[12]};
  const float* bk[3]  = {(const float*)d_in[3],  (const float*)d_in[8],  (const float*)d_in[13]};
  const float* gk[3]  = {(const float*)d_in[4],  (const float*)d_in[9],  (const float*)d_in[14]};
  const float* btk[3] = {(const float*)d_in[5],  (const float*)d_in[10], (const float*)d_in[15]};
  const float* pk[3]  = {(const float*)d_in[6],  (const float*)d_in[11], (const float*)d_in[16]};
  const float* Wm = (const float*)d_in[17];
  const float* bm = (const float*)d_in[18];
  float* out = (float*)d_out;

  // ---- workspace carve (float units); feature buffers channel-major [64][NTOT] ----
  float* ws = (float*)d_ws;
  size_t off = 0;
  auto alloc = [&](size_t nfl) {
    float* ptr = ws + off;
    off += (nfl + 63) & ~(size_t)63;
    return ptr;
  };
  float* bufXW = alloc((size_t)NTOT * 64);
  float* bufH  = alloc((size_t)NTOT * 64);
  float* bufX  = alloc((size_t)NTOT * 64);
  float* dinv_g = alloc(NTOT);
  float* score  = alloc(NTOT);
  float* stanh_g = alloc(NTOT);
  int*   snext_g = (int*)alloc(NTOT);
  uint32_t* packed = (uint32_t*)alloc(EDGES);
  uint16_t* csr    = (uint16_t*)alloc((size_t)NGR * CPAD / 2);
  uint32_t* rs     = (uint32_t*)alloc(NGR * 1025);
  float* sums3 = alloc(3 * 128);
  float* readout = alloc(NGR * 2 * HID);

  pack_init<<<NGR, 256, 0, stream>>>(ei, packed, csr, rs, dinv_g, sums3, readout);

  const int   kk[3] = {820, 656, 525};
  const float invn[3] = {1.0f / (float)NTOT, 1.0f / (float)(NGR * 820),
                         1.0f / (float)(NGR * 656)};

  for (int L = 0; L < 3; L++) {
    float* sums = sums3 + L * 128;
    if (L == 0)
      gemm8<128, false><<<NTOT / 256, 256, 0, stream>>>(x, Wk[0], bufXW);
    else
      gemm8<64, true><<<NTOT / 256, 256, 0, stream>>>(bufX, Wk[L], bufXW);
    edge_agg<<<8 * NGR, 1024, 0, stream>>>(csr, rs, dinv_g, bufXW, bk[L], bufH, sums);
    score_kernel<<<4 * NGR, 256, 0, stream>>>(bufH, sums, gk[L], btk[L], pk[L],
                                              dinv_g, score, stanh_g, invn[L]);
    topk_kernel<<<4 * NGR, 1024, 0, stream>>>(score, snext_g, kk[L]);
    pool_kernel<<<8 * NGR, 256, 0, stream>>>(bufH, sums, gk[L], btk[L],
                                             stanh_g, snext_g, csr, rs,
                                             (L < 2) ? bufX : nullptr, dinv_g,
                                             readout, kk[L], invn[L],
                                             (L < 2) ? 1 : 0);
  }
  final_linear<<<5, 256, 0, stream>>>(readout, Wm, bm, out);
}

// Round 8
// 464.283 us; speedup vs baseline: 1.1587x; 1.0338x over previous
//
#include <hip/hip_runtime.h>
#include <cmath>
#include <cstdint>
#include <cstddef>

#define HID 64
#define NGR 128            // B graphs
#define NTOT 131072        // 128 * 1024 nodes, fixed index space all layers
#define EDGES 1048576      // B * 1024 * 8
#define EPG 8192           // edges per graph
#define CPAD 9216          // padded CSR stride (u16): 8192 + 1024 worst-case pads
#define SENT 1024          // sentinel src index -> reads 0

// ---------- once: pack edges (registers), degree hist, even-padded CSR, dinv ----------
// 32 edges/thread held in registers between the histogram and scatter phases
// (no packed[] global round-trip: saves 8 MB of traffic + the buffer).
__global__ __launch_bounds__(256) void pack_init(
    const int* __restrict__ ei,
    uint16_t* __restrict__ csr_g, uint32_t* __restrict__ rs_g,
    float* __restrict__ dinv_g, float* __restrict__ sums3,
    float* __restrict__ readout) {
  __shared__ int hist[1024];
  __shared__ int part[256];
  __shared__ int cursor[1024];
  int b = blockIdx.x, t = threadIdx.x;
  for (int i = t; i < 1024; i += 256) hist[i] = 0;
  __syncthreads();
  int ebase = b * EPG, nbase = b << 10;
  uint32_t pk[32];                     // 32 = EPG/256 edges per thread
#pragma unroll
  for (int r = 0; r < 32; r++) {
    int e = t + r * 256;
    uint32_t s = (uint32_t)(ei[ebase + e] - nbase);
    uint32_t d = (uint32_t)(ei[EDGES + ebase + e] - nbase);
    pk[r] = s | (d << 10);
    atomicAdd(&hist[(int)d], 1);
  }
  __syncthreads();
  int h0 = hist[t * 4], h1 = hist[t * 4 + 1], h2 = hist[t * 4 + 2], h3 = hist[t * 4 + 3];
  // even-padded row lengths
  int p0 = h0 + (h0 & 1), p1 = h1 + (h1 & 1), p2 = h2 + (h2 & 1), p3 = h3 + (h3 & 1);
  int tot = p0 + p1 + p2 + p3;
  part[t] = tot;
  __syncthreads();
  for (int off = 1; off < 256; off <<= 1) {
    int v = (t >= off) ? part[t - off] : 0;
    __syncthreads();
    part[t] += v;
    __syncthreads();
  }
  int excl = part[t] - tot;
  int r0 = excl, r1 = r0 + p0, r2 = r1 + p1, r3 = r2 + p2;
  cursor[t * 4 + 0] = r0; cursor[t * 4 + 1] = r1;
  cursor[t * 4 + 2] = r2; cursor[t * 4 + 3] = r3;
  uint32_t* rg = rs_g + b * 1025;
  rg[t * 4 + 0] = r0; rg[t * 4 + 1] = r1; rg[t * 4 + 2] = r2; rg[t * 4 + 3] = r3;
  if (t == 255) rg[1024] = part[255];           // total padded length
  for (int i = t; i < 1024; i += 256)
    dinv_g[(b << 10) + i] = rsqrtf((float)hist[i] + 1.0f);
  __syncthreads();
  uint16_t* cg = csr_g + (size_t)b * CPAD;
#pragma unroll
  for (int r = 0; r < 32; r++) {
    int d = (pk[r] >> 10) & 1023;
    int idx = atomicAdd(&cursor[d], 1);
    cg[idx] = (uint16_t)(pk[r] & 1023);
  }
  __syncthreads();
  // sentinel fill for odd rows (cursor[d] == pstart[d] + hist[d] now)
  for (int d = t; d < 1024; d += 256)
    if (hist[d] & 1) cg[cursor[d]] = (uint16_t)SENT;
  if (b < 3 && t < 128) sums3[b * 128 + t] = 0.0f;
  if (t < 128) readout[b * 128 + t] = 0.0f;
}

// ---------- xw^T = (X @ W)^T.  256-node x 64-ch tile, thread = 8 nodes x 8 ch ----------
// X row-major [N,DIN] (TIN=0) or channel-major [DIN,N] (TIN=1). Output XWT [64][N].
// Round-0 measured-best variant (45.6-46.6 us across six structural alternatives).
template<int DIN, bool TIN>
__global__ __launch_bounds__(256, 2) void gemm_xw(
    const float* __restrict__ X, const float* __restrict__ W,
    float* __restrict__ XWT, int n_nodes) {
  __shared__ float sW[32 * 64];        // 8 KB   (k-major, ch inner)
  __shared__ float sX[32 * 260];       // 33.3 KB (k-major, node inner, pad 4)
  const int t = threadIdx.x;
  const int c8 = (t & 7) * 8;
  const int n8 = (t >> 3) * 8;
  const int node0 = blockIdx.x * 256;
  const size_t Nn = (size_t)n_nodes;
  float acc[8][8];
#pragma unroll
  for (int n = 0; n < 8; n++)
#pragma unroll
    for (int c = 0; c < 8; c++) acc[n][c] = 0.0f;

  for (int k0 = 0; k0 < DIN; k0 += 32) {
    // stage 32 rows of W (512 float4, 2 per thread)
    ((float4*)sW)[t]       = ((const float4*)(W + (size_t)k0 * HID))[t];
    ((float4*)sW)[t + 256] = ((const float4*)(W + (size_t)k0 * HID))[t + 256];
    if (TIN) {
      // X [DIN][N]: 32 rows x 256 cols = 2048 f4, 8 per thread
#pragma unroll
      for (int it = 0; it < 8; it++) {
        int slot = t + it * 256;
        int row = slot >> 6, col4 = (slot & 63) * 4;
        *(float4*)(sX + row * 260 + col4) =
            *(const float4*)(X + (size_t)(k0 + row) * Nn + node0 + col4);
      }
    } else {
      // X [N][DIN]: 256 node-rows x 32-k chunk; transpose into LDS
      int i4 = (t & 7) * 4, nn = t >> 3;          // nn 0..31
#pragma unroll
      for (int rep = 0; rep < 8; rep++) {
        int node = nn + rep * 32;
        float4 v = *(const float4*)(X + (size_t)(node0 + node) * DIN + k0 + i4);
        sX[(i4 + 0) * 260 + node] = v.x;
        sX[(i4 + 1) * 260 + node] = v.y;
        sX[(i4 + 2) * 260 + node] = v.z;
        sX[(i4 + 3) * 260 + node] = v.w;
      }
    }
    __syncthreads();
#pragma unroll 4
    for (int i = 0; i < 32; i++) {
      float4 w0 = *(const float4*)(sW + i * 64 + c8);
      float4 w1 = *(const float4*)(sW + i * 64 + c8 + 4);
      float4 x0 = *(const float4*)(sX + i * 260 + n8);
      float4 x1 = *(const float4*)(sX + i * 260 + n8 + 4);
      float xn[8] = {x0.x, x0.y, x0.z, x0.w, x1.x, x1.y, x1.z, x1.w};
      float wn[8] = {w0.x, w0.y, w0.z, w0.w, w1.x, w1.y, w1.z, w1.w};
#pragma unroll
      for (int n = 0; n < 8; n++)
#pragma unroll
        for (int c = 0; c < 8; c++)
          acc[n][c] = fmaf(xn[n], wn[c], acc[n][c]);
    }
    __syncthreads();
  }
#pragma unroll
  for (int cc = 0; cc < 8; cc++) {
    float* o = XWT + (size_t)(c8 + cc) * Nn + node0 + n8;
    *(float4*)(o + 0) = make_float4(acc[0][cc], acc[1][cc], acc[2][cc], acc[3][cc]);
    *(float4*)(o + 4) = make_float4(acc[4][cc], acc[5][cc], acc[6][cc], acc[7][cc]);
  }
}

// ---------- CSR aggregate (paired u32 src reads) + self-loop + bias + BN sums ----------
__global__ __launch_bounds__(1024, 8) void edge_agg(
    const uint16_t* __restrict__ csr_g, const uint32_t* __restrict__ rs_g,
    const float* __restrict__ dinv_g, const float* __restrict__ xwT,
    const float* __restrict__ bias, float* __restrict__ hT,
    float* __restrict__ sums) {
  __shared__ float xws[8 * 1028];      // prescaled xw*dinv; index 1024 = sentinel 0
  __shared__ float dv[1024];
  __shared__ uint32_t rs[1025];
  __shared__ uint32_t csr_s[CPAD / 2]; // 4608 u32 = 18.4 KB (pairs of u16 srcs)
  __shared__ float sredS[16][8], sredQ[16][8];
  const int g = blockIdx.x & 127;
  const int q = blockIdx.x >> 7;
  const int c0 = q * 8;
  const int t = threadIdx.x;
  const int gbase = g << 10;

  dv[t] = dinv_g[gbase + t];
  rs[t] = rs_g[g * 1025 + t];
  if (t == 0) rs[1024] = rs_g[g * 1025 + 1024];
  {
    const uint4* src4 = (const uint4*)(csr_g + (size_t)g * CPAD);
    ((uint4*)csr_s)[t] = src4[t];
    if (t < CPAD / 8 - 1024) ((uint4*)csr_s)[1024 + t] = src4[1024 + t];
  }
  for (int slot = t; slot < 2048; slot += 1024) {
    int c = slot >> 8, pos4 = (slot & 255) * 4;
    float4 v = *(const float4*)(xwT + (size_t)(c0 + c) * NTOT + gbase + pos4);
    float4 dd = *(const float4*)(dinv_g + gbase + pos4);
    v.x *= dd.x; v.y *= dd.y; v.z *= dd.z; v.w *= dd.w;
    *(float4*)(xws + c * 1028 + pos4) = v;
  }
  if (t < 32) xws[(t >> 2) * 1028 + 1024 + (t & 3)] = 0.0f;   // sentinel slots
  __syncthreads();

  const int c = t & 7, j = t >> 3;
  const float* xc = xws + c * 1028;
  const float bv = bias[c0 + c];
  float* hrow = hT + (size_t)(c0 + c) * NTOT + gbase;
  float S = 0.0f, Q = 0.0f;
  for (int d = j; d < 1024; d += 128) {
    float dvd = dv[d];
    if (dvd == 0.0f) continue;
    int e  = rs[d] >> 1;
    int e1 = rs[d + 1] >> 1;
    float a0 = 0.0f, a1 = 0.0f;
    for (; e < e1; e++) {
      uint32_t pk = csr_s[e];
      a0 += xc[pk & 0xFFFFu];
      a1 += xc[pk >> 16];
    }
    float hv = (a0 + a1 + xc[d]) * dvd + bv;
    hrow[d] = hv;
    S += hv; Q += hv * hv;
  }
#pragma unroll
  for (int m = 8; m < 64; m <<= 1) { S += __shfl_xor(S, m); Q += __shfl_xor(Q, m); }
  {
    int lane = t & 63, w = t >> 6;
    if (lane < 8) { sredS[w][lane] = S; sredQ[w][lane] = Q; }
  }
  __syncthreads();
  if (t < 8) {
    float a = 0.0f;
    for (int w2 = 0; w2 < 16; w2++) a += sredS[w2][t];
    atomicAdd(&sums[c0 + t], a);
  } else if (t < 16) {
    int cc = t - 8;
    float a = 0.0f;
    for (int w2 = 0; w2 < 16; w2++) a += sredQ[w2][cc];
    atomicAdd(&sums[64 + cc + c0], a);
  }
}

// ---------- scores: BN+ReLU+dot(p) per node; grid = NGR*4 x 256 ----------
__global__ __launch_bounds__(256) void score_kernel(
    const float* __restrict__ hT, const float* __restrict__ sums,
    const float* __restrict__ gamma, const float* __restrict__ beta,
    const float* __restrict__ p, const float* __restrict__ dinv_g,
    float* __restrict__ score, float* __restrict__ stanh_g, float inv_n) {
  __shared__ float ssc[64], ssh[64], sp[64];
  __shared__ float sipn;
  int b = blockIdx.x >> 2, seg = (blockIdx.x & 3) << 8;
  int t = threadIdx.x;
  int node = (b << 10) + seg + t;
  if (t < 64) {
    float mu = sums[t] * inv_n;
    float var = fmaxf(sums[64 + t] * inv_n - mu * mu, 0.0f);
    float sc = rsqrtf(var + 1e-5f) * gamma[t];
    ssc[t] = sc; ssh[t] = beta[t] - mu * sc;
    sp[t] = p[t];
  }
  __syncthreads();
  if (t == 0) {
    float s = 0.0f;
    for (int i = 0; i < 64; i++) s += sp[i] * sp[i];
    sipn = rsqrtf(s);
  }
  __syncthreads();
  const float* hp = hT + node;
  float s0 = 0.0f;
#pragma unroll 16
  for (int c = 0; c < 64; c++) {
    float y = fmaxf(fmaf(hp[(size_t)c * NTOT], ssc[c], ssh[c]), 0.0f);
    s0 = fmaf(y, sp[c], s0);
  }
  float v0 = s0 * sipn;
  score[node] = (dinv_g[node] > 0.0f) ? v0 : -INFINITY;
  stanh_g[node] = tanhf(v0);
}

// ---------- topk: 4 blocks/graph, 4-way j-split rank count -> kept mask ----------
__global__ __launch_bounds__(1024) void topk_kernel(
    const float* __restrict__ score, int* __restrict__ snext_g, int k) {
  __shared__ float __align__(16) ssc2[4 * 260];   // quarter q at offset q*260
  int b = blockIdx.x >> 2, p = blockIdx.x & 3;
  int t = threadIdx.x;
  int gbase = b << 10;
  float sv = score[gbase + t];
  ssc2[(t >> 8) * 260 + (t & 255)] = sv;
  __syncthreads();
  int il = t >> 2, jq = t & 3;
  int gi = p * 256 + il;
  float my = ssc2[(gi >> 8) * 260 + (gi & 255)];
  const float4* base = (const float4*)(ssc2 + jq * 260);
  int jbase = jq * 256;
  int r = 0;
#pragma unroll 8
  for (int m = 0; m < 64; m++) {
    float4 v = base[m];
    int j0 = jbase + m * 4;
    r += (v.x > my) || (v.x == my && (j0 + 0) < gi);
    r += (v.y > my) || (v.y == my && (j0 + 1) < gi);
    r += (v.z > my) || (v.z == my && (j0 + 2) < gi);
    r += (v.w > my) || (v.w == my && (j0 + 3) < gi);
  }
  r += __shfl_xor(r, 1);
  r += __shfl_xor(r, 2);
  if (jq == 0) snext_g[gbase + gi] = (r < k) ? 1 : 0;
}

// ---------- masked pool + readout accumulate + next-layer dinv (CSR walk) ----------
__global__ __launch_bounds__(256) void pool_kernel(
    const float* __restrict__ hT, const float* __restrict__ sums,
    const float* __restrict__ gamma, const float* __restrict__ beta,
    const float* __restrict__ stanh_g, const int* __restrict__ snext_g,
    const uint16_t* __restrict__ csr_g, const uint32_t* __restrict__ rs_g,
    float* __restrict__ xT_out, float* __restrict__ dinv_g,
    float* __restrict__ readout, int k, float inv_n, int hasNext) {
  __shared__ float ssc[64], ssh[64];
  __shared__ float sth[1024];
  __shared__ int skn[1025];            // [1024] = 0 for sentinel
  __shared__ float redS[4][8], redM[4][8];
  int g = blockIdx.x & 127, q = blockIdx.x >> 7;
  int t = threadIdx.x;
  int gbase = g << 10;
  if (t < 64) {
    float mu = sums[t] * inv_n;
    float var = fmaxf(sums[64 + t] * inv_n - mu * mu, 0.0f);
    float sc = rsqrtf(var + 1e-5f) * gamma[t];
    ssc[t] = sc; ssh[t] = beta[t] - mu * sc;
  }
  for (int i = t; i < 1024; i += 256) {
    sth[i] = stanh_g[gbase + i];
    skn[i] = snext_g[gbase + i];
  }
  if (t == 0) skn[1024] = 0;
  __syncthreads();
  int lane = t & 63, w = t >> 6;
#pragma unroll
  for (int i = 0; i < 8; i++) {
    int c = q * 8 + i;
    const float* hrow = hT + (size_t)c * NTOT + gbase;
    float* xrow = xT_out ? (xT_out + (size_t)c * NTOT + gbase) : nullptr;
    float scc = ssc[c], shh = ssh[c];
    float S = 0.0f, M = -INFINITY;
    for (int nd = t; nd < 1024; nd += 256) {
      bool kn = skn[nd] != 0;
      float y = fmaxf(fmaf(hrow[nd], scc, shh), 0.0f) * sth[nd];
      y = kn ? y : 0.0f;
      if (xrow) xrow[nd] = y;
      S += y;
      if (kn) M = fmaxf(M, y);
    }
#pragma unroll
    for (int m = 1; m < 64; m <<= 1) {
      S += __shfl_xor(S, m);
      M = fmaxf(M, __shfl_xor(M, m));
    }
    if (lane == 0) { redS[w][i] = S; redM[w][i] = M; }
  }
  if (hasNext && t < 128) {
    int d = q * 128 + t;
    if (skn[d]) {
      uint32_t e0 = rs_g[g * 1025 + d], e1 = rs_g[g * 1025 + d + 1];
      const uint16_t* row = csr_g + (size_t)g * CPAD;
      int cnt = 0;
      for (uint32_t e = e0; e < e1; e++) cnt += skn[row[e]];   // sentinel -> 0
      dinv_g[gbase + d] = rsqrtf((float)cnt + 1.0f);
    } else {
      dinv_g[gbase + d] = 0.0f;
    }
  }
  __syncthreads();
  if (t < 8) {
    float S = redS[0][t] + redS[1][t] + redS[2][t] + redS[3][t];
    readout[g * 128 + q * 8 + t] += S / (float)k;
  } else if (t < 16) {
    int i = t - 8;
    float M = fmaxf(fmaxf(redM[0][i], redM[1][i]), fmaxf(redM[2][i], redM[3][i]));
    readout[g * 128 + 64 + q * 8 + i] += M;
  }
}

// ---------------- out = readout @ Wm + bm ----------------
__global__ __launch_bounds__(256) void final_linear(
    const float* __restrict__ readout, const float* __restrict__ Wm,
    const float* __restrict__ bm, float* __restrict__ out) {
  int idx = blockIdx.x * 256 + threadIdx.x;
  if (idx >= NGR * 10) return;
  int b = idx / 10, o = idx - b * 10;
  float acc = bm[o];
  const float* r = readout + (size_t)b * 128;
  for (int c = 0; c < 128; c++) acc = fmaf(r[c], Wm[c * 10 + o], acc);
  out[idx] = acc;
}

extern "C" void kernel_launch(void* const* d_in, const int* in_sizes, int n_in,
                              void* d_out, int out_size, void* d_ws, size_t ws_size,
                              hipStream_t stream) {
  (void)in_sizes; (void)n_in; (void)out_size; (void)ws_size;
  const float* x  = (const float*)d_in[0];
  const int*   ei = (const int*)d_in[1];
  const float* Wk[3]  = {(const float*)d_in[2],  (const float*)d_in[7],  (const float*)d_in[12]};
  const float* bk[3]  = {(const float*)d_in[3],  (const float*)d_in[8],  (const float*)d_in[13]};
  const float* gk[3]  = {(const float*)d_in[4],  (const float*)d_in[9],  (const float*)d_in[14]};
  const float* btk[3] = {(const float*)d_in[5],  (const float*)d_in[10], (const float*)d_in[15]};
  const float* pk[3]  = {(const float*)d_in[6],  (const float*)d_in[11], (const float*)d_in[16]};
  const float* Wm = (const float*)d_in[17];
  const float* bm = (const float*)d_in[18];
  float* out = (float*)d_out;

  // ---- workspace carve (float units); feature buffers channel-major [64][NTOT] ----
  float* ws = (float*)d_ws;
  size_t off = 0;
  auto alloc = [&](size_t nfl) {
    float* ptr = ws + off;
    off += (nfl + 63) & ~(size_t)63;
    return ptr;
  };
  float* bufXW = alloc((size_t)NTOT * 64);
  float* bufH  = alloc((size_t)NTOT * 64);
  float* bufX  = alloc((size_t)NTOT * 64);
  float* dinv_g = alloc(NTOT);
  float* score  = alloc(NTOT);
  float* stanh_g = alloc(NTOT);
  int*   snext_g = (int*)alloc(NTOT);
  uint16_t* csr    = (uint16_t*)alloc((size_t)NGR * CPAD / 2);
  uint32_t* rs     = (uint32_t*)alloc(NGR * 1025);
  float* sums3 = alloc(3 * 128);
  float* readout = alloc(NGR * 2 * HID);

  pack_init<<<NGR, 256, 0, stream>>>(ei, csr, rs, dinv_g, sums3, readout);

  const int   kk[3] = {820, 656, 525};
  const float invn[3] = {1.0f / (float)NTOT, 1.0f / (float)(NGR * 820),
                         1.0f / (float)(NGR * 656)};

  for (int L = 0; L < 3; L++) {
    float* sums = sums3 + L * 128;
    if (L == 0)
      gemm_xw<128, false><<<NTOT / 256, 256, 0, stream>>>(x, Wk[0], bufXW, NTOT);
    else
      gemm_xw<64, true><<<NTOT / 256, 256, 0, stream>>>(bufX, Wk[L], bufXW, NTOT);
    edge_agg<<<8 * NGR, 1024, 0, stream>>>(csr, rs, dinv_g, bufXW, bk[L], bufH, sums);
    score_kernel<<<4 * NGR, 256, 0, stream>>>(bufH, sums, gk[L], btk[L], pk[L],
                                              dinv_g, score, stanh_g, invn[L]);
    topk_kernel<<<4 * NGR, 1024, 0, stream>>>(score, snext_g, kk[L]);
    pool_kernel<<<8 * NGR, 256, 0, stream>>>(bufH, sums, gk[L], btk[L],
                                             stanh_g, snext_g, csr, rs,
                                             (L < 2) ? bufX : nullptr, dinv_g,
                                             readout, kk[L], invn[L],
                                             (L < 2) ? 1 : 0);
  }
  final_linear<<<5, 256, 0, stream>>>(readout, Wm, bm, out);
}

// Round 9
// 462.308 us; speedup vs baseline: 1.1637x; 1.0043x over previous
//
#include <hip/hip_runtime.h>
#include <cmath>
#include <cstdint>
#include <cstddef>

#define HID 64
#define NGR 128            // B graphs
#define NTOT 131072        // 128 * 1024 nodes, fixed index space all layers
#define EDGES 1048576      // B * 1024 * 8
#define EPG 8192           // edges per graph
#define CPAD 9216          // padded CSR stride (u16): 8192 + 1024 worst-case pads
#define SENT 1024          // sentinel src index -> reads 0

// ---------- once: pack edges (registers), degree hist, even-padded CSR, dinv ----------
__global__ __launch_bounds__(256) void pack_init(
    const int* __restrict__ ei,
    uint16_t* __restrict__ csr_g, uint32_t* __restrict__ rs_g,
    float* __restrict__ dinv_g, float* __restrict__ sums3,
    float* __restrict__ readout) {
  __shared__ int hist[1024];
  __shared__ int part[256];
  __shared__ int cursor[1024];
  int b = blockIdx.x, t = threadIdx.x;
  for (int i = t; i < 1024; i += 256) hist[i] = 0;
  __syncthreads();
  int ebase = b * EPG, nbase = b << 10;
  uint32_t pk[32];                     // 32 = EPG/256 edges per thread
#pragma unroll
  for (int r = 0; r < 32; r++) {
    int e = t + r * 256;
    uint32_t s = (uint32_t)(ei[ebase + e] - nbase);
    uint32_t d = (uint32_t)(ei[EDGES + ebase + e] - nbase);
    pk[r] = s | (d << 10);
    atomicAdd(&hist[(int)d], 1);
  }
  __syncthreads();
  int h0 = hist[t * 4], h1 = hist[t * 4 + 1], h2 = hist[t * 4 + 2], h3 = hist[t * 4 + 3];
  // even-padded row lengths
  int p0 = h0 + (h0 & 1), p1 = h1 + (h1 & 1), p2 = h2 + (h2 & 1), p3 = h3 + (h3 & 1);
  int tot = p0 + p1 + p2 + p3;
  part[t] = tot;
  __syncthreads();
  for (int off = 1; off < 256; off <<= 1) {
    int v = (t >= off) ? part[t - off] : 0;
    __syncthreads();
    part[t] += v;
    __syncthreads();
  }
  int excl = part[t] - tot;
  int r0 = excl, r1 = r0 + p0, r2 = r1 + p1, r3 = r2 + p2;
  cursor[t * 4 + 0] = r0; cursor[t * 4 + 1] = r1;
  cursor[t * 4 + 2] = r2; cursor[t * 4 + 3] = r3;
  uint32_t* rg = rs_g + b * 1025;
  rg[t * 4 + 0] = r0; rg[t * 4 + 1] = r1; rg[t * 4 + 2] = r2; rg[t * 4 + 3] = r3;
  if (t == 255) rg[1024] = part[255];           // total padded length
  for (int i = t; i < 1024; i += 256)
    dinv_g[(b << 10) + i] = rsqrtf((float)hist[i] + 1.0f);
  __syncthreads();
  uint16_t* cg = csr_g + (size_t)b * CPAD;
#pragma unroll
  for (int r = 0; r < 32; r++) {
    int d = (pk[r] >> 10) & 1023;
    int idx = atomicAdd(&cursor[d], 1);
    cg[idx] = (uint16_t)(pk[r] & 1023);
  }
  __syncthreads();
  // sentinel fill for odd rows (cursor[d] == pstart[d] + hist[d] now)
  for (int d = t; d < 1024; d += 256)
    if (hist[d] & 1) cg[cursor[d]] = (uint16_t)SENT;
  if (b < 3 && t < 128) sums3[b * 128 + t] = 0.0f;
  if (t < 128) readout[b * 128 + t] = 0.0f;
}

// ---------- layer-0 gemm: xw^T = (X @ W)^T, X row-major [N][128] ----------
// Round-0 measured-best structure (256-node x 64-ch tile, 8x8/thread).
template<int DIN>
__global__ __launch_bounds__(256, 2) void gemm_xw(
    const float* __restrict__ X, const float* __restrict__ W,
    float* __restrict__ XWT) {
  __shared__ float sW[32 * 64];        // 8 KB   (k-major, ch inner)
  __shared__ float sX[32 * 260];       // 33.3 KB (k-major, node inner, pad 4)
  const int t = threadIdx.x;
  const int c8 = (t & 7) * 8;
  const int n8 = (t >> 3) * 8;
  const int node0 = blockIdx.x * 256;
  float acc[8][8];
#pragma unroll
  for (int n = 0; n < 8; n++)
#pragma unroll
    for (int c = 0; c < 8; c++) acc[n][c] = 0.0f;

  for (int k0 = 0; k0 < DIN; k0 += 32) {
    // stage 32 rows of W (512 float4, 2 per thread)
    ((float4*)sW)[t]       = ((const float4*)(W + (size_t)k0 * HID))[t];
    ((float4*)sW)[t + 256] = ((const float4*)(W + (size_t)k0 * HID))[t + 256];
    // X [N][DIN]: 256 node-rows x 32-k chunk; transpose into LDS
    {
      int i4 = (t & 7) * 4, nn = t >> 3;          // nn 0..31
#pragma unroll
      for (int rep = 0; rep < 8; rep++) {
        int node = nn + rep * 32;
        float4 v = *(const float4*)(X + (size_t)(node0 + node) * DIN + k0 + i4);
        sX[(i4 + 0) * 260 + node] = v.x;
        sX[(i4 + 1) * 260 + node] = v.y;
        sX[(i4 + 2) * 260 + node] = v.z;
        sX[(i4 + 3) * 260 + node] = v.w;
      }
    }
    __syncthreads();
#pragma unroll 4
    for (int i = 0; i < 32; i++) {
      float4 w0 = *(const float4*)(sW + i * 64 + c8);
      float4 w1 = *(const float4*)(sW + i * 64 + c8 + 4);
      float4 x0 = *(const float4*)(sX + i * 260 + n8);
      float4 x1 = *(const float4*)(sX + i * 260 + n8 + 4);
      float xn[8] = {x0.x, x0.y, x0.z, x0.w, x1.x, x1.y, x1.z, x1.w};
      float wn[8] = {w0.x, w0.y, w0.z, w0.w, w1.x, w1.y, w1.z, w1.w};
#pragma unroll
      for (int n = 0; n < 8; n++)
#pragma unroll
        for (int c = 0; c < 8; c++)
          acc[n][c] = fmaf(xn[n], wn[c], acc[n][c]);
    }
    __syncthreads();
  }
#pragma unroll
  for (int cc = 0; cc < 8; cc++) {
    float* o = XWT + (size_t)(c8 + cc) * NTOT + node0 + n8;
    *(float4*)(o + 0) = make_float4(acc[0][cc], acc[1][cc], acc[2][cc], acc[3][cc]);
    *(float4*)(o + 4) = make_float4(acc[4][cc], acc[5][cc], acc[6][cc], acc[7][cc]);
  }
}

// ---------- layers 1,2 gemm: xw^T = ((BN_relu(H)*mult) @ W)^T ----------
// Same structure as gemm_xw TIN=1 (measured-best), but the BN+ReLU+mult
// transform is applied IN THE STAGING PHASE (latency-stalled anyway: VALUBusy
// 30%), not the FMA loop. mult[node] = kept ? tanh(score) : 0 from topk.
// This removes pool's 33 MB bufX write; inner loop is untouched.
__global__ __launch_bounds__(256, 2) void gemm_bn(
    const float* __restrict__ H, const float* __restrict__ sums,
    const float* __restrict__ gamma, const float* __restrict__ beta,
    const float* __restrict__ mult_g, const float* __restrict__ W,
    float* __restrict__ XWT, float inv_n) {
  __shared__ float sW[32 * 64];        // 8 KB
  __shared__ float sX[32 * 260];       // 33.3 KB
  __shared__ float ssc[64], ssh[64];
  const int t = threadIdx.x;
  const int c8 = (t & 7) * 8;
  const int n8 = (t >> 3) * 8;
  const int node0 = blockIdx.x * 256;
  if (t < 64) {
    float mu = sums[t] * inv_n;
    float var = fmaxf(sums[64 + t] * inv_n - mu * mu, 0.0f);
    float sc = rsqrtf(var + 1e-5f) * gamma[t];
    ssc[t] = sc; ssh[t] = beta[t] - mu * sc;
  }
  const int col4 = (t & 63) * 4;       // invariant across k0 -> hoist mult load
  const float4 m4 = *(const float4*)(mult_g + node0 + col4);
  __syncthreads();

  float acc[8][8];
#pragma unroll
  for (int n = 0; n < 8; n++)
#pragma unroll
    for (int c = 0; c < 8; c++) acc[n][c] = 0.0f;

  for (int k0 = 0; k0 < 64; k0 += 32) {
    ((float4*)sW)[t]       = ((const float4*)(W + (size_t)k0 * HID))[t];
    ((float4*)sW)[t + 256] = ((const float4*)(W + (size_t)k0 * HID))[t + 256];
    // H [64][NTOT]: 32 rows x 256 cols = 2048 f4, 8 per thread; BN in staging
#pragma unroll
    for (int it = 0; it < 8; it++) {
      int slot = t + it * 256;
      int row = slot >> 6;             // 0..31  (col4 fixed per thread)
      float4 v = *(const float4*)(H + (size_t)(k0 + row) * NTOT + node0 + col4);
      float sc = ssc[k0 + row], sh = ssh[k0 + row];
      v.x = fmaxf(fmaf(v.x, sc, sh), 0.0f) * m4.x;
      v.y = fmaxf(fmaf(v.y, sc, sh), 0.0f) * m4.y;
      v.z = fmaxf(fmaf(v.z, sc, sh), 0.0f) * m4.z;
      v.w = fmaxf(fmaf(v.w, sc, sh), 0.0f) * m4.w;
      *(float4*)(sX + row * 260 + col4) = v;
    }
    __syncthreads();
#pragma unroll 4
    for (int i = 0; i < 32; i++) {
      float4 w0 = *(const float4*)(sW + i * 64 + c8);
      float4 w1 = *(const float4*)(sW + i * 64 + c8 + 4);
      float4 x0 = *(const float4*)(sX + i * 260 + n8);
      float4 x1 = *(const float4*)(sX + i * 260 + n8 + 4);
      float xn[8] = {x0.x, x0.y, x0.z, x0.w, x1.x, x1.y, x1.z, x1.w};
      float wn[8] = {w0.x, w0.y, w0.z, w0.w, w1.x, w1.y, w1.z, w1.w};
#pragma unroll
      for (int n = 0; n < 8; n++)
#pragma unroll
        for (int c = 0; c < 8; c++)
          acc[n][c] = fmaf(xn[n], wn[c], acc[n][c]);
    }
    __syncthreads();
  }
#pragma unroll
  for (int cc = 0; cc < 8; cc++) {
    float* o = XWT + (size_t)(c8 + cc) * NTOT + node0 + n8;
    *(float4*)(o + 0) = make_float4(acc[0][cc], acc[1][cc], acc[2][cc], acc[3][cc]);
    *(float4*)(o + 4) = make_float4(acc[4][cc], acc[5][cc], acc[6][cc], acc[7][cc]);
  }
}

// ---------- CSR aggregate (paired u32 src reads) + self-loop + bias + BN sums ----------
__global__ __launch_bounds__(1024, 8) void edge_agg(
    const uint16_t* __restrict__ csr_g, const uint32_t* __restrict__ rs_g,
    const float* __restrict__ dinv_g, const float* __restrict__ xwT,
    const float* __restrict__ bias, float* __restrict__ hT,
    float* __restrict__ sums) {
  __shared__ float xws[8 * 1028];      // prescaled xw*dinv; index 1024 = sentinel 0
  __shared__ float dv[1024];
  __shared__ uint32_t rs[1025];
  __shared__ uint32_t csr_s[CPAD / 2]; // 4608 u32 = 18.4 KB (pairs of u16 srcs)
  __shared__ float sredS[16][8], sredQ[16][8];
  const int g = blockIdx.x & 127;
  const int q = blockIdx.x >> 7;
  const int c0 = q * 8;
  const int t = threadIdx.x;
  const int gbase = g << 10;

  dv[t] = dinv_g[gbase + t];
  rs[t] = rs_g[g * 1025 + t];
  if (t == 0) rs[1024] = rs_g[g * 1025 + 1024];
  {
    const uint4* src4 = (const uint4*)(csr_g + (size_t)g * CPAD);
    ((uint4*)csr_s)[t] = src4[t];
    if (t < CPAD / 8 - 1024) ((uint4*)csr_s)[1024 + t] = src4[1024 + t];
  }
  for (int slot = t; slot < 2048; slot += 1024) {
    int c = slot >> 8, pos4 = (slot & 255) * 4;
    float4 v = *(const float4*)(xwT + (size_t)(c0 + c) * NTOT + gbase + pos4);
    float4 dd = *(const float4*)(dinv_g + gbase + pos4);
    v.x *= dd.x; v.y *= dd.y; v.z *= dd.z; v.w *= dd.w;
    *(float4*)(xws + c * 1028 + pos4) = v;
  }
  if (t < 32) xws[(t >> 2) * 1028 + 1024 + (t & 3)] = 0.0f;   // sentinel slots
  __syncthreads();

  const int c = t & 7, j = t >> 3;
  const float* xc = xws + c * 1028;
  const float bv = bias[c0 + c];
  float* hrow = hT + (size_t)(c0 + c) * NTOT + gbase;
  float S = 0.0f, Q = 0.0f;
  for (int d = j; d < 1024; d += 128) {
    float dvd = dv[d];
    if (dvd == 0.0f) continue;
    int e  = rs[d] >> 1;
    int e1 = rs[d + 1] >> 1;
    float a0 = 0.0f, a1 = 0.0f;
    for (; e < e1; e++) {
      uint32_t pk = csr_s[e];
      a0 += xc[pk & 0xFFFFu];
      a1 += xc[pk >> 16];
    }
    float hv = (a0 + a1 + xc[d]) * dvd + bv;
    hrow[d] = hv;
    S += hv; Q += hv * hv;
  }
#pragma unroll
  for (int m = 8; m < 64; m <<= 1) { S += __shfl_xor(S, m); Q += __shfl_xor(Q, m); }
  {
    int lane = t & 63, w = t >> 6;
    if (lane < 8) { sredS[w][lane] = S; sredQ[w][lane] = Q; }
  }
  __syncthreads();
  if (t < 8) {
    float a = 0.0f;
    for (int w2 = 0; w2 < 16; w2++) a += sredS[w2][t];
    atomicAdd(&sums[c0 + t], a);
  } else if (t < 16) {
    int cc = t - 8;
    float a = 0.0f;
    for (int w2 = 0; w2 < 16; w2++) a += sredQ[w2][cc];
    atomicAdd(&sums[64 + cc + c0], a);
  }
}

// ---------- scores: BN+ReLU+dot(p) per node; grid = NGR*4 x 256 ----------
__global__ __launch_bounds__(256) void score_kernel(
    const float* __restrict__ hT, const float* __restrict__ sums,
    const float* __restrict__ gamma, const float* __restrict__ beta,
    const float* __restrict__ p, const float* __restrict__ dinv_g,
    float* __restrict__ score, float* __restrict__ stanh_g, float inv_n) {
  __shared__ float ssc[64], ssh[64], sp[64];
  __shared__ float sipn;
  int b = blockIdx.x >> 2, seg = (blockIdx.x & 3) << 8;
  int t = threadIdx.x;
  int node = (b << 10) + seg + t;
  if (t < 64) {
    float mu = sums[t] * inv_n;
    float var = fmaxf(sums[64 + t] * inv_n - mu * mu, 0.0f);
    float sc = rsqrtf(var + 1e-5f) * gamma[t];
    ssc[t] = sc; ssh[t] = beta[t] - mu * sc;
    sp[t] = p[t];
  }
  __syncthreads();
  if (t == 0) {
    float s = 0.0f;
    for (int i = 0; i < 64; i++) s += sp[i] * sp[i];
    sipn = rsqrtf(s);
  }
  __syncthreads();
  const float* hp = hT + node;
  float s0 = 0.0f;
#pragma unroll 16
  for (int c = 0; c < 64; c++) {
    float y = fmaxf(fmaf(hp[(size_t)c * NTOT], ssc[c], ssh[c]), 0.0f);
    s0 = fmaf(y, sp[c], s0);
  }
  float v0 = s0 * sipn;
  score[node] = (dinv_g[node] > 0.0f) ? v0 : -INFINITY;
  stanh_g[node] = tanhf(v0);
}

// ---------- topk: 4 blocks/graph, rank count -> kept mask + mult ----------
__global__ __launch_bounds__(1024) void topk_kernel(
    const float* __restrict__ score, const float* __restrict__ stanh_g,
    int* __restrict__ snext_g, float* __restrict__ mult_g, int k) {
  __shared__ float __align__(16) ssc2[4 * 260];   // quarter q at offset q*260
  int b = blockIdx.x >> 2, p = blockIdx.x & 3;
  int t = threadIdx.x;
  int gbase = b << 10;
  float sv = score[gbase + t];
  ssc2[(t >> 8) * 260 + (t & 255)] = sv;
  __syncthreads();
  int il = t >> 2, jq = t & 3;
  int gi = p * 256 + il;
  float my = ssc2[(gi >> 8) * 260 + (gi & 255)];
  const float4* base = (const float4*)(ssc2 + jq * 260);
  int jbase = jq * 256;
  int r = 0;
#pragma unroll 8
  for (int m = 0; m < 64; m++) {
    float4 v = base[m];
    int j0 = jbase + m * 4;
    r += (v.x > my) || (v.x == my && (j0 + 0) < gi);
    r += (v.y > my) || (v.y == my && (j0 + 1) < gi);
    r += (v.z > my) || (v.z == my && (j0 + 2) < gi);
    r += (v.w > my) || (v.w == my && (j0 + 3) < gi);
  }
  r += __shfl_xor(r, 1);
  r += __shfl_xor(r, 2);
  if (jq == 0) {
    int kn = (r < k) ? 1 : 0;
    snext_g[gbase + gi] = kn;
    mult_g[gbase + gi] = kn ? stanh_g[gbase + gi] : 0.0f;
  }
}

// ---------- pool: readout S/M accumulate + next-layer dinv (no x write) ----------
__global__ __launch_bounds__(256) void pool_kernel(
    const float* __restrict__ hT, const float* __restrict__ sums,
    const float* __restrict__ gamma, const float* __restrict__ beta,
    const float* __restrict__ mult_g, const int* __restrict__ snext_g,
    const uint16_t* __restrict__ csr_g, const uint32_t* __restrict__ rs_g,
    float* __restrict__ dinv_g,
    float* __restrict__ readout, int k, float inv_n, int hasNext) {
  __shared__ float ssc[64], ssh[64];
  __shared__ float sth[1024];          // holds mult (kept ? tanh : 0)
  __shared__ int skn[1025];            // [1024] = 0 for sentinel
  __shared__ float redS[4][8], redM[4][8];
  int g = blockIdx.x & 127, q = blockIdx.x >> 7;
  int t = threadIdx.x;
  int gbase = g << 10;
  if (t < 64) {
    float mu = sums[t] * inv_n;
    float var = fmaxf(sums[64 + t] * inv_n - mu * mu, 0.0f);
    float sc = rsqrtf(var + 1e-5f) * gamma[t];
    ssc[t] = sc; ssh[t] = beta[t] - mu * sc;
  }
  for (int i = t; i < 1024; i += 256) {
    sth[i] = mult_g[gbase + i];
    skn[i] = snext_g[gbase + i];
  }
  if (t == 0) skn[1024] = 0;
  __syncthreads();
  int lane = t & 63, w = t >> 6;
#pragma unroll
  for (int i = 0; i < 8; i++) {
    int c = q * 8 + i;
    const float* hrow = hT + (size_t)c * NTOT + gbase;
    float scc = ssc[c], shh = ssh[c];
    float S = 0.0f, M = -INFINITY;
    for (int nd = t; nd < 1024; nd += 256) {
      float y = fmaxf(fmaf(hrow[nd], scc, shh), 0.0f) * sth[nd];  // 0 if dropped
      S += y;
      if (skn[nd]) M = fmaxf(M, y);
    }
#pragma unroll
    for (int m = 1; m < 64; m <<= 1) {
      S += __shfl_xor(S, m);
      M = fmaxf(M, __shfl_xor(M, m));
    }
    if (lane == 0) { redS[w][i] = S; redM[w][i] = M; }
  }
  if (hasNext && t < 128) {
    int d = q * 128 + t;
    if (skn[d]) {
      uint32_t e0 = rs_g[g * 1025 + d], e1 = rs_g[g * 1025 + d + 1];
      const uint16_t* row = csr_g + (size_t)g * CPAD;
      int cnt = 0;
      for (uint32_t e = e0; e < e1; e++) cnt += skn[row[e]];   // sentinel -> 0
      dinv_g[gbase + d] = rsqrtf((float)cnt + 1.0f);
    } else {
      dinv_g[gbase + d] = 0.0f;
    }
  }
  __syncthreads();
  if (t < 8) {
    float S = redS[0][t] + redS[1][t] + redS[2][t] + redS[3][t];
    readout[g * 128 + q * 8 + t] += S / (float)k;
  } else if (t < 16) {
    int i = t - 8;
    float M = fmaxf(fmaxf(redM[0][i], redM[1][i]), fmaxf(redM[2][i], redM[3][i]));
    readout[g * 128 + 64 + q * 8 + i] += M;
  }
}

// ---------------- out = readout @ Wm + bm ----------------
__global__ __launch_bounds__(256) void final_linear(
    const float* __restrict__ readout, const float* __restrict__ Wm,
    const float* __restrict__ bm, float* __restrict__ out) {
  int idx = blockIdx.x * 256 + threadIdx.x;
  if (idx >= NGR * 10) return;
  int b = idx / 10, o = idx - b * 10;
  float acc = bm[o];
  const float* r = readout + (size_t)b * 128;
  for (int c = 0; c < 128; c++) acc = fmaf(r[c], Wm[c * 10 + o], acc);
  out[idx] = acc;
}

extern "C" void kernel_launch(void* const* d_in, const int* in_sizes, int n_in,
                              void* d_out, int out_size, void* d_ws, size_t ws_size,
                              hipStream_t stream) {
  (void)in_sizes; (void)n_in; (void)out_size; (void)ws_size;
  const float* x  = (const float*)d_in[0];
  const int*   ei = (const int*)d_in[1];
  const float* Wk[3]  = {(const float*)d_in[2],  (const float*)d_in[7],  (const float*)d_in[12]};
  const float* bk[3]  = {(const float*)d_in[3],  (const float*)d_in[8],  (const float*)d_in[13]};
  const float* gk[3]  = {(const float*)d_in[4],  (const float*)d_in[9],  (const float*)d_in[14]};
  const float* btk[3] = {(const float*)d_in[5],  (const float*)d_in[10], (const float*)d_in[15]};
  const float* pk[3]  = {(const float*)d_in[6],  (const float*)d_in[11], (const float*)d_in[16]};
  const float* Wm = (const float*)d_in[17];
  const float* bm = (const float*)d_in[18];
  float* out = (float*)d_out;

  // ---- workspace carve (float units); feature buffers channel-major [64][NTOT] ----
  float* ws = (float*)d_ws;
  size_t off = 0;
  auto alloc = [&](size_t nfl) {
    float* ptr = ws + off;
    off += (nfl + 63) & ~(size_t)63;
    return ptr;
  };
  float* bufXW = alloc((size_t)NTOT * 64);
  float* bufH  = alloc((size_t)NTOT * 64);
  float* dinv_g = alloc(NTOT);
  float* score  = alloc(NTOT);
  float* stanh_g = alloc(NTOT);
  float* mult   = alloc(NTOT);
  int*   snext_g = (int*)alloc(NTOT);
  uint16_t* csr    = (uint16_t*)alloc((size_t)NGR * CPAD / 2);
  uint32_t* rs     = (uint32_t*)alloc(NGR * 1025);
  float* sums3 = alloc(3 * 128);
  float* readout = alloc(NGR * 2 * HID);

  pack_init<<<NGR, 256, 0, stream>>>(ei, csr, rs, dinv_g, sums3, readout);

  const int   kk[3] = {820, 656, 525};
  const float invn[3] = {1.0f / (float)NTOT, 1.0f / (float)(NGR * 820),
                         1.0f / (float)(NGR * 656)};

  for (int L = 0; L < 3; L++) {
    float* sums = sums3 + L * 128;
    if (L == 0)
      gemm_xw<128><<<NTOT / 256, 256, 0, stream>>>(x, Wk[0], bufXW);
    else
      gemm_bn<<<NTOT / 256, 256, 0, stream>>>(bufH, sums3 + (L - 1) * 128,
                                              gk[L - 1], btk[L - 1], mult,
                                              Wk[L], bufXW, invn[L - 1]);
    edge_agg<<<8 * NGR, 1024, 0, stream>>>(csr, rs, dinv_g, bufXW, bk[L], bufH, sums);
    score_kernel<<<4 * NGR, 256, 0, stream>>>(bufH, sums, gk[L], btk[L], pk[L],
                                              dinv_g, score, stanh_g, invn[L]);
    topk_kernel<<<4 * NGR, 1024, 0, stream>>>(score, stanh_g, snext_g, mult, kk[L]);
    pool_kernel<<<8 * NGR, 256, 0, stream>>>(bufH, sums, gk[L], btk[L],
                                             mult, snext_g, csr, rs,
                                             dinv_g, readout, kk[L], invn[L],
                                             (L < 2) ? 1 : 0);
  }
  final_linear<<<5, 256, 0, stream>>>(readout, Wm, bm, out);
}